// Round 17
// baseline (3274.082 us; speedup 1.0000x reference)
//
#include <hip/hip_runtime.h>
#include <hip/hip_bf16.h>

#define DEV __device__ __forceinline__

typedef __attribute__((ext_vector_type(8))) __bf16 bf16x8;
typedef __attribute__((ext_vector_type(4))) float f32x4;
typedef __attribute__((ext_vector_type(4))) short short4v;

DEV void gload_lds16(const void* g, void* l) {
  __builtin_amdgcn_global_load_lds((const __attribute__((address_space(1))) void*)g,
                                   (__attribute__((address_space(3))) void*)l, 16, 0, 0);
}

DEV short f2bf_s(float f) {
  __hip_bfloat16 h = __float2bfloat16(f);
  return __builtin_bit_cast(short, h);
}

// ---------------- weight prep: fp32 [L][K][N] -> bf16 [L][N][K] (optionally scaled) ------
__global__ __launch_bounds__(256)
void transpose_to_bf16(const float* __restrict__ src, __hip_bfloat16* __restrict__ dst,
                       int K, int N, size_t srcLayerStride, size_t dstLayerStride,
                       float scale) {
  __shared__ float t[32][33];
  const int n0 = blockIdx.x * 32, k0 = blockIdx.y * 32;
  const float* s = src + (size_t)blockIdx.z * srcLayerStride;
  __hip_bfloat16* d = dst + (size_t)blockIdx.z * dstLayerStride;
  const int tx = threadIdx.x & 31, ty = threadIdx.x >> 5;  // 32 x 8
#pragma unroll
  for (int j = 0; j < 4; ++j)
    t[ty + j * 8][tx] = s[(size_t)(k0 + ty + j * 8) * N + n0 + tx];
  __syncthreads();
#pragma unroll
  for (int j = 0; j < 4; ++j)
    d[(size_t)(n0 + ty + j * 8) * K + k0 + tx] = __float2bfloat16(t[tx][ty + j * 8] * scale);
}

// ---------------- pack QKV biases: [L][3072] = [bq*s | bk | bv] ----------------
__global__ __launch_bounds__(256)
void pack_qkv_bias(const float* __restrict__ bq, const float* __restrict__ bk,
                   const float* __restrict__ bv, float* __restrict__ out, float qs) {
  int idx = blockIdx.x * 256 + threadIdx.x;  // L*3072 total
  int l = idx / 3072, j = idx % 3072;
  float v;
  if (j < 1024) v = bq[l * 1024 + j] * qs;
  else if (j < 2048) v = bk[l * 1024 + j - 1024];
  else v = bv[l * 1024 + j - 2048];
  out[idx] = v;
}

// ---------------- x init: copy fp32 + bf16 shadow ----------------
__global__ __launch_bounds__(256)
void init_x(const float* __restrict__ xin, float* __restrict__ xf,
            __hip_bfloat16* __restrict__ xb, int n4) {
  int i = blockIdx.x * 256 + threadIdx.x;
  if (i < n4) {
    float4 v = ((const float4*)xin)[i];
    ((float4*)xf)[i] = v;
    __hip_bfloat16* o = xb + (size_t)i * 4;
    o[0] = __float2bfloat16(v.x); o[1] = __float2bfloat16(v.y);
    o[2] = __float2bfloat16(v.z); o[3] = __float2bfloat16(v.w);
  }
}

// ---------------- GEMM (single-buffer, m97 structure): multi-block/CU grids ----------------
// AHM: A physically head-major [K/64][M][64]
// CHM: C physically head-major. For the QKV GEMM (CHM=true):
//   cols <  2048 (Q,K thirds): [col/64][M][64]   (row-major per head)
//   cols >= 2048 (V third):    [col/64][64][M]   (COLUMN-major per head) — attn then
//   stages V with dense b128 loads (transpose done for free in this epilogue).
template <bool OUT_BF16, bool RELU, bool AHM, bool CHM>
__global__ __launch_bounds__(256, 2)
void gemm_bt(const __hip_bfloat16* __restrict__ A, const __hip_bfloat16* __restrict__ Bt,
             const float* __restrict__ bias, void* __restrict__ Cout,
             int M, int N, int K) {
  __shared__ __align__(16) short lA[128 * 64];
  __shared__ __align__(16) short lB[128 * 64];
  const int tid = threadIdx.x;
  const int lane = tid & 63, w = tid >> 6;
  const int m0 = blockIdx.y * 128, n0 = blockIdx.x * 128;
  const int wr = w >> 1, wc = w & 1;
  const int lr = lane & 15, lg = lane >> 4;
  const int srow = lane >> 3, scol = (lane & 7) * 8;
  f32x4 acc[4][4] = {};
  const short* Asrc = (const short*)A;
  const short* Bsrc = (const short*)Bt;
  for (int k0 = 0; k0 < K; k0 += 64) {
#pragma unroll
    for (int i = 0; i < 4; ++i) {
      int s = w * 4 + i;
      const short* ap;
      if (AHM)
        ap = Asrc + ((size_t)(k0 >> 6) * M + (m0 + s * 8 + srow)) * 64 + scol;
      else
        ap = Asrc + (size_t)(m0 + s * 8 + srow) * K + k0 + scol;
      gload_lds16(ap, lA + s * 512);
    }
#pragma unroll
    for (int i = 0; i < 4; ++i) {
      int s = w * 4 + i;
      gload_lds16(Bsrc + (size_t)(n0 + s * 8 + srow) * K + k0 + scol, lB + s * 512);
    }
    __syncthreads();
#pragma unroll
    for (int kk = 0; kk < 2; ++kk) {
      const int lk = kk * 32 + lg * 8;
      bf16x8 af[4], bfr[4];
#pragma unroll
      for (int mr = 0; mr < 4; ++mr)
        af[mr] = *(const bf16x8*)&lA[(wr * 64 + mr * 16 + lr) * 64 + lk];
#pragma unroll
      for (int nc = 0; nc < 4; ++nc)
        bfr[nc] = *(const bf16x8*)&lB[(wc * 64 + nc * 16 + lr) * 64 + lk];
#pragma unroll
      for (int mr = 0; mr < 4; ++mr)
#pragma unroll
        for (int nc = 0; nc < 4; ++nc)
          acc[mr][nc] = __builtin_amdgcn_mfma_f32_16x16x32_bf16(af[mr], bfr[nc], acc[mr][nc], 0, 0, 0);
    }
    __syncthreads();
  }
  if (CHM && n0 >= 2048) {
    // V third: column-major per head. 4 consecutive rows pack into one 8B store.
#pragma unroll
    for (int mr = 0; mr < 4; ++mr)
#pragma unroll
      for (int nc = 0; nc < 4; ++nc) {
        const int col = n0 + wc * 64 + nc * 16 + lr;
        const float bv = bias[col];
        const int row0 = m0 + wr * 64 + mr * 16 + lg * 4;
        short4v pack;
#pragma unroll
        for (int r = 0; r < 4; ++r) pack[r] = f2bf_s(acc[mr][nc][r] + bv);
        *(short4v*)((short*)Cout + ((size_t)(col >> 6) * 64 + (col & 63)) * M + row0) = pack;
      }
    return;
  }
#pragma unroll
  for (int mr = 0; mr < 4; ++mr)
#pragma unroll
    for (int nc = 0; nc < 4; ++nc) {
      const int col = n0 + wc * 64 + nc * 16 + lr;
      const float bv = bias[col];
#pragma unroll
      for (int r = 0; r < 4; ++r) {
        const int row = m0 + wr * 64 + mr * 16 + lg * 4 + r;
        float vv = acc[mr][nc][r] + bv;
        if (RELU) vv = fmaxf(vv, 0.f);
        size_t cidx;
        if (CHM) cidx = ((size_t)(col >> 6) * M + row) * 64 + (col & 63);
        else cidx = (size_t)row * N + col;
        if (OUT_BF16)
          ((__hip_bfloat16*)Cout)[cidx] = __float2bfloat16(vv);
        else
          ((float*)Cout)[cidx] = vv;
      }
    }
}

// ---------------- split-K GEMM (2-phase dbuf, z = K-half; no bias) ----------------
// For N=1024 GEMMs (O-proj AHM=true, FFN2 AHM=false). 512 blocks = 2/CU.
// Partials go to TWO DISJOINT dead buffers C0/C1 (r14 lesson: never alias A).
template <bool AHM>
__global__ __launch_bounds__(256, 2)
void gemm_sk(const __hip_bfloat16* __restrict__ A, const __hip_bfloat16* __restrict__ Bt,
             float* __restrict__ C0, float* __restrict__ C1, int M, int N, int K) {
  __shared__ __align__(16) short lA[2][128 * 64];
  __shared__ __align__(16) short lB[2][128 * 64];
  const int tid = threadIdx.x;
  const int lane = tid & 63, w = tid >> 6;
  const int m0 = blockIdx.y * 128, n0 = blockIdx.x * 128;
  const int z = blockIdx.z;
  const int Ksub = K >> 1, kbase = z * Ksub;
  const int wr = w >> 1, wc = w & 1;
  const int lr = lane & 15, lg = lane >> 4;
  const int srow = lane >> 3, scol = (lane & 7) * 8;
  f32x4 acc[4][4] = {};
  const short* Asrc = (const short*)A;
  const short* Bsrc = (const short*)Bt;
  const int KT = Ksub >> 6;

  auto stage = [&](int buf, int t) {
    const int kc = kbase + t * 64;
#pragma unroll
    for (int i = 0; i < 4; ++i) {
      int s = w * 4 + i;
      const short* ap;
      if (AHM)
        ap = Asrc + ((size_t)(kc >> 6) * M + (m0 + s * 8 + srow)) * 64 + scol;
      else
        ap = Asrc + (size_t)(m0 + s * 8 + srow) * K + kc + scol;
      gload_lds16(ap, &lA[buf][s * 512]);
      gload_lds16(Bsrc + (size_t)(n0 + s * 8 + srow) * K + kc + scol, &lB[buf][s * 512]);
    }
  };

  stage(0, 0);
  __syncthreads();

  int cur = 0;
  for (int t = 0; t < KT; ++t) {
    if (t + 1 < KT) stage(cur ^ 1, t + 1);
    const short* cA = lA[cur];
    const short* cB = lB[cur];
#pragma unroll
    for (int kk = 0; kk < 2; ++kk) {
      const int lk = kk * 32 + lg * 8;
      bf16x8 af[4], bfr[4];
#pragma unroll
      for (int mr = 0; mr < 4; ++mr)
        af[mr] = *(const bf16x8*)&cA[(wr * 64 + mr * 16 + lr) * 64 + lk];
#pragma unroll
      for (int nc = 0; nc < 4; ++nc)
        bfr[nc] = *(const bf16x8*)&cB[(wc * 64 + nc * 16 + lr) * 64 + lk];
      __builtin_amdgcn_s_setprio(1);
#pragma unroll
      for (int mr = 0; mr < 4; ++mr)
#pragma unroll
        for (int nc = 0; nc < 4; ++nc)
          acc[mr][nc] = __builtin_amdgcn_mfma_f32_16x16x32_bf16(af[mr], bfr[nc], acc[mr][nc], 0, 0, 0);
      __builtin_amdgcn_s_setprio(0);
    }
    __syncthreads();
    cur ^= 1;
  }

  float* Cz = z ? C1 : C0;
#pragma unroll
  for (int mr = 0; mr < 4; ++mr)
#pragma unroll
    for (int nc = 0; nc < 4; ++nc) {
      const int col = n0 + wc * 64 + nc * 16 + lr;
#pragma unroll
      for (int r = 0; r < 4; ++r) {
        const int row = m0 + wr * 64 + mr * 16 + lg * 4 + r;
        Cz[(size_t)row * N + col] = acc[mr][nc][r];
      }
    }
}

// ---------------- flash attention: Q,K head-major [.][M][64]; V COLUMN-major [.][64][M] ---
// r16 inner code, re-geometried to 8-WAVE blocks (512 thr, 256 q-rows):
//  - K/V staging shared by 8 waves (2 b128 loads + 2 b128 LDS writes/thread, was 4+4)
//  - LDS 64KB (lP grows to [256][64]) -> 2 blocks/CU = 16 waves/CU (was 8)
//  - XCD pinning kept: 4 heads/XCD (2MB K/V resident in the 4MB private L2)
// Loads issue-and-consume (DO NOT prefetch — r5/r9 13x overfetch); lP wave-private.
__global__ __launch_bounds__(512, 4)
void attn_kernel(const __hip_bfloat16* __restrict__ qkv_hm, __hip_bfloat16* __restrict__ o_hm,
                 int Mtot) {
  const int S = 2048;
  __shared__ __align__(16) short lK[128 * 64];    // [key][64],  swz chunk ^ (key&7)
  __shared__ __align__(16) short lVt[64 * 128];   // [d][128],   swz chunk ^ (d&15)
  __shared__ __align__(16) short lP[256 * 64];    // [qr][64],   swz chunk ^ (qr&7); wave-private rows
  const int tid = threadIdx.x, lane = tid & 63, w = tid >> 6;  // w in 0..7
  const int bid = blockIdx.x;                     // 256 blocks
  const int xcd = bid & 7, u = bid >> 3;          // u in 0..31
  const int gh = (u >> 3) * 8 + xcd;              // 0..31 = (b,h); 4 head-groups/XCD
  const int qt = u & 7;                           // 8 q-tiles of 256 rows
  const int b = gh >> 4, h = gh & 15;
  const int lr = lane & 15, lg = lane >> 4;

  const short* qp = (const short*)qkv_hm + (size_t)h * Mtot * 64;
  const short* kp = (const short*)qkv_hm + (size_t)(16 + h) * Mtot * 64;
  const short* vp = (const short*)qkv_hm + (size_t)(32 + h) * Mtot * 64;  // [64][M]

  const size_t qrow0 = (size_t)b * S + (size_t)qt * 256 + w * 32;
  bf16x8 qf[2][2];
#pragma unroll
  for (int mr = 0; mr < 2; ++mr)
#pragma unroll
    for (int kk = 0; kk < 2; ++kk)
      qf[mr][kk] = *(const bf16x8*)(qp + (qrow0 + mr * 16 + lr) * 64 + kk * 32 + lg * 8);

  f32x4 oacc[2][4] = {};
  float mrun[2][4], lrun[2][4];
#pragma unroll
  for (int mr = 0; mr < 2; ++mr)
#pragma unroll
    for (int r = 0; r < 4; ++r) { mrun[mr][r] = -1e30f; lrun[mr][r] = 0.f; }

  for (int kt = 0; kt < S / 128; ++kt) {
    const size_t krow0 = (size_t)b * S + (size_t)kt * 128;
    // ---- global loads (issue-and-consume: self-synchronizing; DO NOT prefetch) ----
    bf16x8 kreg[2], vreg[2];
#pragma unroll
    for (int i = 0; i < 2; ++i) {
      int slot = tid + 512 * i;  // 1024 16B-chunks: 128 keys x 8
      kreg[i] = *(const bf16x8*)(kp + krow0 * 64 + slot * 8);
    }
#pragma unroll
    for (int i = 0; i < 2; ++i) {
      int slot = tid + 512 * i;  // 1024 16B-chunks: 64 d-rows x 16
      int d = slot >> 4, ck = slot & 15;
      vreg[i] = *(const bf16x8*)(vp + (size_t)d * Mtot + krow0 + ck * 8);
    }
    // ---- LDS writes (both b128, swizzled) ----
#pragma unroll
    for (int i = 0; i < 2; ++i) {
      int slot = tid + 512 * i;
      int r = slot >> 3, c = slot & 7;
      *(bf16x8*)&lK[r * 64 + ((c ^ (r & 7)) << 3)] = kreg[i];
    }
#pragma unroll
    for (int i = 0; i < 2; ++i) {
      int slot = tid + 512 * i;
      int d = slot >> 4, ck = slot & 15;
      *(bf16x8*)&lVt[d * 128 + ((ck ^ (d & 15)) << 3)] = vreg[i];
    }
    __syncthreads();

    // ---- QK^T (1/sqrt(dk) pre-folded into Wq/bq) ----
    f32x4 sf[2][8] = {};
    __builtin_amdgcn_s_setprio(1);
#pragma unroll
    for (int kk = 0; kk < 2; ++kk) {
      bf16x8 bfr[8];
#pragma unroll
      for (int nb = 0; nb < 8; ++nb)
        bfr[nb] = *(const bf16x8*)&lK[(nb * 16 + lr) * 64 + (((kk * 4 + lg) ^ (lr & 7)) << 3)];
#pragma unroll
      for (int mr = 0; mr < 2; ++mr)
#pragma unroll
        for (int nb = 0; nb < 8; ++nb)
          sf[mr][nb] = __builtin_amdgcn_mfma_f32_16x16x32_bf16(qf[mr][kk], bfr[nb], sf[mr][nb], 0, 0, 0);
    }
    __builtin_amdgcn_s_setprio(0);

    // ---- row max over ALL keys; rescale oacc ----
    float ls[2][4];
#pragma unroll
    for (int mr = 0; mr < 2; ++mr) {
      float pm[4] = {-1e30f, -1e30f, -1e30f, -1e30f};
#pragma unroll
      for (int nb = 0; nb < 8; ++nb)
#pragma unroll
        for (int r = 0; r < 4; ++r) pm[r] = fmaxf(pm[r], sf[mr][nb][r]);
#pragma unroll
      for (int off = 1; off < 16; off <<= 1)
#pragma unroll
        for (int r = 0; r < 4; ++r) pm[r] = fmaxf(pm[r], __shfl_xor(pm[r], off));
#pragma unroll
      for (int r = 0; r < 4; ++r) {
        float nm = fmaxf(mrun[mr][r], pm[r]);
        float fac = __expf(mrun[mr][r] - nm);
        mrun[mr][r] = nm;
        lrun[mr][r] *= fac;
        ls[mr][r] = 0.f;
#pragma unroll
        for (int nd = 0; nd < 4; ++nd) oacc[mr][nd][r] *= fac;
      }
    }

    // ---- two key-halves: {exp + lP write} then {PV 2 kk}; PV MFMAs overlap next exps ----
#pragma unroll
    for (int half = 0; half < 2; ++half) {
#pragma unroll
      for (int mr = 0; mr < 2; ++mr)
#pragma unroll
        for (int nb = half * 4; nb < half * 4 + 4; ++nb)
#pragma unroll
          for (int r = 0; r < 4; ++r) {
            float p = __expf(sf[mr][nb][r] - mrun[mr][r]);
            ls[mr][r] += p;
            const int rr = w * 32 + mr * 16 + lg * 4 + r;
            const int c = (nb - half * 4) * 16 + lr;  // half-local column 0..63
            lP[rr * 64 + (((c >> 3) ^ (rr & 7)) << 3) + (c & 7)] = f2bf_s(p);
          }
      __builtin_amdgcn_s_setprio(1);
#pragma unroll
      for (int kkh = 0; kkh < 2; ++kkh) {
        const int kkg = half * 2 + kkh;
        bf16x8 pa[2], bv[4];
#pragma unroll
        for (int mr = 0; mr < 2; ++mr) {
          const int rr = w * 32 + mr * 16 + lr;
          pa[mr] = *(const bf16x8*)&lP[rr * 64 + (((kkh * 4 + lg) ^ (rr & 7)) << 3)];
        }
#pragma unroll
        for (int nd = 0; nd < 4; ++nd) {
          const int rd = nd * 16 + lr;
          bv[nd] = *(const bf16x8*)&lVt[rd * 128 + (((kkg * 4 + lg) ^ lr) << 3)];
        }
#pragma unroll
        for (int mr = 0; mr < 2; ++mr)
#pragma unroll
          for (int nd = 0; nd < 4; ++nd)
            oacc[mr][nd] = __builtin_amdgcn_mfma_f32_16x16x32_bf16(pa[mr], bv[nd], oacc[mr][nd], 0, 0, 0);
      }
      __builtin_amdgcn_s_setprio(0);
    }

    // ---- deferred sum reduce ----
#pragma unroll
    for (int mr = 0; mr < 2; ++mr) {
#pragma unroll
      for (int off = 1; off < 16; off <<= 1)
#pragma unroll
        for (int r = 0; r < 4; ++r) ls[mr][r] += __shfl_xor(ls[mr][r], off);
#pragma unroll
      for (int r = 0; r < 4; ++r) lrun[mr][r] += ls[mr][r];
    }
    __syncthreads();  // protect lK/lVt/lP overwrite next iteration
  }

  __hip_bfloat16* op = o_hm + (size_t)h * Mtot * 64;
#pragma unroll
  for (int mr = 0; mr < 2; ++mr) {
    float inv[4];
#pragma unroll
    for (int r = 0; r < 4; ++r) inv[r] = 1.0f / lrun[mr][r];
#pragma unroll
    for (int nd = 0; nd < 4; ++nd)
#pragma unroll
      for (int r = 0; r < 4; ++r) {
        size_t row = qrow0 + mr * 16 + lg * 4 + r;
        int col = nd * 16 + lr;
        op[row * 64 + col] = __float2bfloat16(oacc[mr][nd][r] * inv[r]);
      }
  }
}

// ---------------- fused residual + layernorm (fp32 in, fp32 + bf16 out) ----------------
// NY=2: y = y0 + y1 + bias (split-K partials).
template <int NY>
__global__ __launch_bounds__(256)
void residual_ln(const float* __restrict__ xin, const float* __restrict__ y0,
                 const float* __restrict__ y1, const float* __restrict__ bias,
                 const float* __restrict__ g, const float* __restrict__ beta,
                 float* __restrict__ xout, __hip_bfloat16* __restrict__ xb) {
  const int D = 1024;
  const int row = blockIdx.x, t = threadIdx.x;
  const float4 xv = ((const float4*)(xin + (size_t)row * D))[t];
  float4 yv = ((const float4*)(y0 + (size_t)row * D))[t];
  if (NY == 2) {
    const float4 y1v = ((const float4*)(y1 + (size_t)row * D))[t];
    const float4 bv2 = ((const float4*)bias)[t];
    yv.x += y1v.x + bv2.x; yv.y += y1v.y + bv2.y;
    yv.z += y1v.z + bv2.z; yv.w += y1v.w + bv2.w;
  }
  float va0 = xv.x + yv.x, va1 = xv.y + yv.y, va2 = xv.z + yv.z, va3 = xv.w + yv.w;
  __shared__ float red[4];
  float s = va0 + va1 + va2 + va3;
#pragma unroll
  for (int off = 32; off; off >>= 1) s += __shfl_xor(s, off);
  if ((t & 63) == 0) red[t >> 6] = s;
  __syncthreads();
  const float mu = (red[0] + red[1] + red[2] + red[3]) * (1.0f / D);
  __syncthreads();
  float d0 = va0 - mu, d1 = va1 - mu, d2 = va2 - mu, d3 = va3 - mu;
  float ss = d0 * d0 + d1 * d1 + d2 * d2 + d3 * d3;
#pragma unroll
  for (int off = 32; off; off >>= 1) ss += __shfl_xor(ss, off);
  if ((t & 63) == 0) red[t >> 6] = ss;
  __syncthreads();
  const float var = (red[0] + red[1] + red[2] + red[3]) * (1.0f / D);
  const float rstd = rsqrtf(var + 1e-5f);
  const float4 gv = ((const float4*)g)[t];
  const float4 bv = ((const float4*)beta)[t];
  float o0 = d0 * rstd * gv.x + bv.x;
  float o1 = d1 * rstd * gv.y + bv.y;
  float o2 = d2 * rstd * gv.z + bv.z;
  float o3 = d3 * rstd * gv.w + bv.w;
  ((float4*)(xout + (size_t)row * D))[t] = make_float4(o0, o1, o2, o3);
  __hip_bfloat16* ob = xb + (size_t)row * D + (size_t)t * 4;
  ob[0] = __float2bfloat16(o0); ob[1] = __float2bfloat16(o1);
  ob[2] = __float2bfloat16(o2); ob[3] = __float2bfloat16(o3);
}

// ---------------- launcher ----------------
extern "C" void kernel_launch(void* const* d_in, const int* in_sizes, int n_in,
                              void* d_out, int out_size, void* d_ws, size_t ws_size,
                              hipStream_t stream) {
  const int L = 6, D = 1024, DFF = 4096, B = 2, S = 2048, M = B * S;
  const float* x_in = (const float*)d_in[0];
  const float* Wq = (const float*)d_in[1];
  const float* bq = (const float*)d_in[2];
  const float* Wk = (const float*)d_in[3];
  const float* bk = (const float*)d_in[4];
  const float* Wv = (const float*)d_in[5];
  const float* bvp = (const float*)d_in[6];
  const float* Wo = (const float*)d_in[7];
  const float* bo = (const float*)d_in[8];
  const float* g1 = (const float*)d_in[9];
  const float* be1 = (const float*)d_in[10];
  const float* W1 = (const float*)d_in[11];
  const float* b1 = (const float*)d_in[12];
  const float* W2 = (const float*)d_in[13];
  const float* b2 = (const float*)d_in[14];
  const float* g2 = (const float*)d_in[15];
  const float* be2 = (const float*)d_in[16];

  char* base = (char*)d_ws;
  size_t off = 0;
  auto carve = [&](size_t bytes) {
    char* p = base + off;
    off += (bytes + 255) & ~(size_t)255;
    return p;
  };
  const size_t LAYER_ELEMS = 4 * (size_t)D * D + 2 * (size_t)D * DFF;  // 12,582,912
  __hip_bfloat16* wT = (__hip_bfloat16*)carve(L * LAYER_ELEMS * 2);
  float* bqkv = (float*)carve((size_t)L * 3 * D * 4);
  float* xf = (float*)carve((size_t)M * D * 4);
  __hip_bfloat16* xb = (__hip_bfloat16*)carve((size_t)M * D * 2);
  __hip_bfloat16* qkvb = (__hip_bfloat16*)carve((size_t)M * 3 * D * 2);  // q,k: [h][M][64]; v: [h][64][M]; 24MB
  __hip_bfloat16* ob = (__hip_bfloat16*)carve((size_t)M * D * 2);        // head-major [16][M][64], 8MB
  __hip_bfloat16* hb = (__hip_bfloat16*)carve((size_t)M * DFF * 2);      // 32MB
  float* yf = (float*)carve((size_t)M * D * 4);                          // 16MB
  if (off > ws_size) return;
  // split-K partials: TWO DISJOINT dead regions, neither aliasing the GEMM's A input.
  float* p0 = (float*)qkvb;
  float* p1 = yf;

  dim3 blk(256);
  const float qscale = 0.03125f;  // 1/sqrt(1024) = 2^-5, exact in bf16
  transpose_to_bf16<<<dim3(D / 32, D / 32, L), blk, 0, stream>>>(
      Wq, wT + 0 * (size_t)D * D, D, D, (size_t)D * D, LAYER_ELEMS, qscale);
  transpose_to_bf16<<<dim3(D / 32, D / 32, L), blk, 0, stream>>>(
      Wk, wT + 1 * (size_t)D * D, D, D, (size_t)D * D, LAYER_ELEMS, 1.0f);
  transpose_to_bf16<<<dim3(D / 32, D / 32, L), blk, 0, stream>>>(
      Wv, wT + 2 * (size_t)D * D, D, D, (size_t)D * D, LAYER_ELEMS, 1.0f);
  transpose_to_bf16<<<dim3(D / 32, D / 32, L), blk, 0, stream>>>(
      Wo, wT + 3 * (size_t)D * D, D, D, (size_t)D * D, LAYER_ELEMS, 1.0f);
  transpose_to_bf16<<<dim3(DFF / 32, D / 32, L), blk, 0, stream>>>(
      W1, wT + 4 * (size_t)D * D, D, DFF, (size_t)D * DFF, LAYER_ELEMS, 1.0f);
  transpose_to_bf16<<<dim3(D / 32, DFF / 32, L), blk, 0, stream>>>(
      W2, wT + 4 * (size_t)D * D + (size_t)D * DFF, DFF, D, (size_t)D * DFF, LAYER_ELEMS, 1.0f);
  pack_qkv_bias<<<dim3(L * 3 * D / 256), blk, 0, stream>>>(bq, bk, bvp, bqkv, qscale);
  init_x<<<dim3(M * D / 4 / 256), blk, 0, stream>>>(x_in, xf, xb, M * D / 4);

  for (int l = 0; l < L; ++l) {
    const __hip_bfloat16* WqkvT = wT + (size_t)l * LAYER_ELEMS;  // rows: [Wq^T|Wk^T|Wv^T]
    const __hip_bfloat16* WoT = WqkvT + 3 * (size_t)D * D;
    const __hip_bfloat16* W1T = WoT + (size_t)D * D;
    const __hip_bfloat16* W2T = W1T + (size_t)D * DFF;
    gemm_bt<true, false, false, true><<<dim3(3 * D / 128, M / 128), blk, 0, stream>>>(
        xb, WqkvT, bqkv + (size_t)l * 3 * D, qkvb, M, 3 * D, D);
    attn_kernel<<<dim3(256), dim3(512), 0, stream>>>(qkvb, ob, M);
    // O-proj: split-K x2; partials p0 (=qkvb, dead) + p1 (=yf); LN1 sums (+bias bo)
    gemm_sk<true><<<dim3(D / 128, M / 128, 2), blk, 0, stream>>>(
        ob, WoT, p0, p1, M, D, D);
    residual_ln<2><<<dim3(M), blk, 0, stream>>>(
        xf, p0, p1, bo + (size_t)l * D,
        g1 + (size_t)l * D, be1 + (size_t)l * D, xf, xb);
    gemm_bt<true, true, false, false><<<dim3(DFF / 128, M / 128), blk, 0, stream>>>(
        xb, W1T, b1 + (size_t)l * DFF, hb, M, DFF, D);
    // FFN2: split-K x2; partials p0 + p1; LN2 sums (+bias b2)
    gemm_sk<false><<<dim3(D / 128, M / 128, 2), blk, 0, stream>>>(
        hb, W2T, p0, p1, M, D, DFF);
    residual_ln<2><<<dim3(M), blk, 0, stream>>>(
        xf, p0, p1, b2 + (size_t)l * D,
        g2 + (size_t)l * D, be2 + (size_t)l * D, xf, xb);
  }

  hipMemcpyAsync(d_out, xf, (size_t)M * D * sizeof(float), hipMemcpyDeviceToDevice, stream);
}

// Round 18
// 1712.798 us; speedup vs baseline: 1.9115x; 1.9115x over previous
//
#include <hip/hip_runtime.h>
#include <hip/hip_bf16.h>

#define DEV __device__ __forceinline__

typedef __attribute__((ext_vector_type(8))) __bf16 bf16x8;
typedef __attribute__((ext_vector_type(4))) float f32x4;
typedef __attribute__((ext_vector_type(4))) short short4v;

DEV void gload_lds16(const void* g, void* l) {
  __builtin_amdgcn_global_load_lds((const __attribute__((address_space(1))) void*)g,
                                   (__attribute__((address_space(3))) void*)l, 16, 0, 0);
}

DEV short f2bf_s(float f) {
  __hip_bfloat16 h = __float2bfloat16(f);
  return __builtin_bit_cast(short, h);
}

// ---------------- weight prep: fp32 [L][K][N] -> bf16 [L][N][K] (optionally scaled) ------
__global__ __launch_bounds__(256)
void transpose_to_bf16(const float* __restrict__ src, __hip_bfloat16* __restrict__ dst,
                       int K, int N, size_t srcLayerStride, size_t dstLayerStride,
                       float scale) {
  __shared__ float t[32][33];
  const int n0 = blockIdx.x * 32, k0 = blockIdx.y * 32;
  const float* s = src + (size_t)blockIdx.z * srcLayerStride;
  __hip_bfloat16* d = dst + (size_t)blockIdx.z * dstLayerStride;
  const int tx = threadIdx.x & 31, ty = threadIdx.x >> 5;  // 32 x 8
#pragma unroll
  for (int j = 0; j < 4; ++j)
    t[ty + j * 8][tx] = s[(size_t)(k0 + ty + j * 8) * N + n0 + tx];
  __syncthreads();
#pragma unroll
  for (int j = 0; j < 4; ++j)
    d[(size_t)(n0 + ty + j * 8) * K + k0 + tx] = __float2bfloat16(t[tx][ty + j * 8] * scale);
}

// ---------------- pack QKV biases: [L][3072] = [bq*s | bk | bv] ----------------
__global__ __launch_bounds__(256)
void pack_qkv_bias(const float* __restrict__ bq, const float* __restrict__ bk,
                   const float* __restrict__ bv, float* __restrict__ out, float qs) {
  int idx = blockIdx.x * 256 + threadIdx.x;  // L*3072 total
  int l = idx / 3072, j = idx % 3072;
  float v;
  if (j < 1024) v = bq[l * 1024 + j] * qs;
  else if (j < 2048) v = bk[l * 1024 + j - 1024];
  else v = bv[l * 1024 + j - 2048];
  out[idx] = v;
}

// ---------------- x init: copy fp32 + bf16 shadow ----------------
__global__ __launch_bounds__(256)
void init_x(const float* __restrict__ xin, float* __restrict__ xf,
            __hip_bfloat16* __restrict__ xb, int n4) {
  int i = blockIdx.x * 256 + threadIdx.x;
  if (i < n4) {
    float4 v = ((const float4*)xin)[i];
    ((float4*)xf)[i] = v;
    __hip_bfloat16* o = xb + (size_t)i * 4;
    o[0] = __float2bfloat16(v.x); o[1] = __float2bfloat16(v.y);
    o[2] = __float2bfloat16(v.z); o[3] = __float2bfloat16(v.w);
  }
}

// ---------------- GEMM (single-buffer, m97 structure): multi-block/CU grids ----------------
// AHM: A physically head-major [K/64][M][64]
// CHM: C physically head-major. For the QKV GEMM (CHM=true):
//   cols <  2048 (Q,K thirds): [col/64][M][64]   (row-major per head)
//   cols >= 2048 (V third):    [col/64][64][M]   (COLUMN-major per head) — attn then
//   stages V with dense b128 loads (transpose done for free in this epilogue).
template <bool OUT_BF16, bool RELU, bool AHM, bool CHM>
__global__ __launch_bounds__(256, 2)
void gemm_bt(const __hip_bfloat16* __restrict__ A, const __hip_bfloat16* __restrict__ Bt,
             const float* __restrict__ bias, void* __restrict__ Cout,
             int M, int N, int K) {
  __shared__ __align__(16) short lA[128 * 64];
  __shared__ __align__(16) short lB[128 * 64];
  const int tid = threadIdx.x;
  const int lane = tid & 63, w = tid >> 6;
  const int m0 = blockIdx.y * 128, n0 = blockIdx.x * 128;
  const int wr = w >> 1, wc = w & 1;
  const int lr = lane & 15, lg = lane >> 4;
  const int srow = lane >> 3, scol = (lane & 7) * 8;
  f32x4 acc[4][4] = {};
  const short* Asrc = (const short*)A;
  const short* Bsrc = (const short*)Bt;
  for (int k0 = 0; k0 < K; k0 += 64) {
#pragma unroll
    for (int i = 0; i < 4; ++i) {
      int s = w * 4 + i;
      const short* ap;
      if (AHM)
        ap = Asrc + ((size_t)(k0 >> 6) * M + (m0 + s * 8 + srow)) * 64 + scol;
      else
        ap = Asrc + (size_t)(m0 + s * 8 + srow) * K + k0 + scol;
      gload_lds16(ap, lA + s * 512);
    }
#pragma unroll
    for (int i = 0; i < 4; ++i) {
      int s = w * 4 + i;
      gload_lds16(Bsrc + (size_t)(n0 + s * 8 + srow) * K + k0 + scol, lB + s * 512);
    }
    __syncthreads();
#pragma unroll
    for (int kk = 0; kk < 2; ++kk) {
      const int lk = kk * 32 + lg * 8;
      bf16x8 af[4], bfr[4];
#pragma unroll
      for (int mr = 0; mr < 4; ++mr)
        af[mr] = *(const bf16x8*)&lA[(wr * 64 + mr * 16 + lr) * 64 + lk];
#pragma unroll
      for (int nc = 0; nc < 4; ++nc)
        bfr[nc] = *(const bf16x8*)&lB[(wc * 64 + nc * 16 + lr) * 64 + lk];
#pragma unroll
      for (int mr = 0; mr < 4; ++mr)
#pragma unroll
        for (int nc = 0; nc < 4; ++nc)
          acc[mr][nc] = __builtin_amdgcn_mfma_f32_16x16x32_bf16(af[mr], bfr[nc], acc[mr][nc], 0, 0, 0);
    }
    __syncthreads();
  }
  if (CHM && n0 >= 2048) {
    // V third: column-major per head. 4 consecutive rows pack into one 8B store.
#pragma unroll
    for (int mr = 0; mr < 4; ++mr)
#pragma unroll
      for (int nc = 0; nc < 4; ++nc) {
        const int col = n0 + wc * 64 + nc * 16 + lr;
        const float bv = bias[col];
        const int row0 = m0 + wr * 64 + mr * 16 + lg * 4;
        short4v pack;
#pragma unroll
        for (int r = 0; r < 4; ++r) pack[r] = f2bf_s(acc[mr][nc][r] + bv);
        *(short4v*)((short*)Cout + ((size_t)(col >> 6) * 64 + (col & 63)) * M + row0) = pack;
      }
    return;
  }
#pragma unroll
  for (int mr = 0; mr < 4; ++mr)
#pragma unroll
    for (int nc = 0; nc < 4; ++nc) {
      const int col = n0 + wc * 64 + nc * 16 + lr;
      const float bv = bias[col];
#pragma unroll
      for (int r = 0; r < 4; ++r) {
        const int row = m0 + wr * 64 + mr * 16 + lg * 4 + r;
        float vv = acc[mr][nc][r] + bv;
        if (RELU) vv = fmaxf(vv, 0.f);
        size_t cidx;
        if (CHM) cidx = ((size_t)(col >> 6) * M + row) * 64 + (col & 63);
        else cidx = (size_t)row * N + col;
        if (OUT_BF16)
          ((__hip_bfloat16*)Cout)[cidx] = __float2bfloat16(vv);
        else
          ((float*)Cout)[cidx] = vv;
      }
    }
}

// ---------------- split-K GEMM (2-phase dbuf, z = K-half; no bias) ----------------
// For N=1024 GEMMs (O-proj AHM=true, FFN2 AHM=false). 512 blocks = 2/CU.
// Partials go to TWO DISJOINT dead buffers C0/C1 (r14 lesson: never alias A).
template <bool AHM>
__global__ __launch_bounds__(256, 2)
void gemm_sk(const __hip_bfloat16* __restrict__ A, const __hip_bfloat16* __restrict__ Bt,
             float* __restrict__ C0, float* __restrict__ C1, int M, int N, int K) {
  __shared__ __align__(16) short lA[2][128 * 64];
  __shared__ __align__(16) short lB[2][128 * 64];
  const int tid = threadIdx.x;
  const int lane = tid & 63, w = tid >> 6;
  const int m0 = blockIdx.y * 128, n0 = blockIdx.x * 128;
  const int z = blockIdx.z;
  const int Ksub = K >> 1, kbase = z * Ksub;
  const int wr = w >> 1, wc = w & 1;
  const int lr = lane & 15, lg = lane >> 4;
  const int srow = lane >> 3, scol = (lane & 7) * 8;
  f32x4 acc[4][4] = {};
  const short* Asrc = (const short*)A;
  const short* Bsrc = (const short*)Bt;
  const int KT = Ksub >> 6;

  auto stage = [&](int buf, int t) {
    const int kc = kbase + t * 64;
#pragma unroll
    for (int i = 0; i < 4; ++i) {
      int s = w * 4 + i;
      const short* ap;
      if (AHM)
        ap = Asrc + ((size_t)(kc >> 6) * M + (m0 + s * 8 + srow)) * 64 + scol;
      else
        ap = Asrc + (size_t)(m0 + s * 8 + srow) * K + kc + scol;
      gload_lds16(ap, &lA[buf][s * 512]);
      gload_lds16(Bsrc + (size_t)(n0 + s * 8 + srow) * K + kc + scol, &lB[buf][s * 512]);
    }
  };

  stage(0, 0);
  __syncthreads();

  int cur = 0;
  for (int t = 0; t < KT; ++t) {
    if (t + 1 < KT) stage(cur ^ 1, t + 1);
    const short* cA = lA[cur];
    const short* cB = lB[cur];
#pragma unroll
    for (int kk = 0; kk < 2; ++kk) {
      const int lk = kk * 32 + lg * 8;
      bf16x8 af[4], bfr[4];
#pragma unroll
      for (int mr = 0; mr < 4; ++mr)
        af[mr] = *(const bf16x8*)&cA[(wr * 64 + mr * 16 + lr) * 64 + lk];
#pragma unroll
      for (int nc = 0; nc < 4; ++nc)
        bfr[nc] = *(const bf16x8*)&cB[(wc * 64 + nc * 16 + lr) * 64 + lk];
      __builtin_amdgcn_s_setprio(1);
#pragma unroll
      for (int mr = 0; mr < 4; ++mr)
#pragma unroll
        for (int nc = 0; nc < 4; ++nc)
          acc[mr][nc] = __builtin_amdgcn_mfma_f32_16x16x32_bf16(af[mr], bfr[nc], acc[mr][nc], 0, 0, 0);
      __builtin_amdgcn_s_setprio(0);
    }
    __syncthreads();
    cur ^= 1;
  }

  float* Cz = z ? C1 : C0;
#pragma unroll
  for (int mr = 0; mr < 4; ++mr)
#pragma unroll
    for (int nc = 0; nc < 4; ++nc) {
      const int col = n0 + wc * 64 + nc * 16 + lr;
#pragma unroll
      for (int r = 0; r < 4; ++r) {
        const int row = m0 + wr * 64 + mr * 16 + lg * 4 + r;
        Cz[(size_t)row * N + col] = acc[mr][nc][r];
      }
    }
}

// ---------------- flash attention: Q,K head-major [.][M][64]; V COLUMN-major [.][64][M] ---
// 8-WAVE blocks (512 thr, 256 q-rows): K/V staging shared by 8 waves; LDS 64KB.
// NO second launch_bounds arg (r17 lesson: "(512,4)" made the allocator cap VGPR at 64
// -> full spill, 605MB scratch writes, 4x slower). Natural ~120 VGPR -> 4 waves/SIMD
// = 2 blocks/CU = 16 waves/CU, which is the occupancy this geometry wants.
// Loads issue-and-consume (DO NOT prefetch — r5/r9 13x overfetch); lP wave-private.
__global__ __launch_bounds__(512)
void attn_kernel(const __hip_bfloat16* __restrict__ qkv_hm, __hip_bfloat16* __restrict__ o_hm,
                 int Mtot) {
  const int S = 2048;
  __shared__ __align__(16) short lK[128 * 64];    // [key][64],  swz chunk ^ (key&7)
  __shared__ __align__(16) short lVt[64 * 128];   // [d][128],   swz chunk ^ (d&15)
  __shared__ __align__(16) short lP[256 * 64];    // [qr][64],   swz chunk ^ (qr&7); wave-private rows
  const int tid = threadIdx.x, lane = tid & 63, w = tid >> 6;  // w in 0..7
  const int bid = blockIdx.x;                     // 256 blocks
  const int xcd = bid & 7, u = bid >> 3;          // u in 0..31
  const int gh = (u >> 3) * 8 + xcd;              // 0..31 = (b,h); 4 head-groups/XCD
  const int qt = u & 7;                           // 8 q-tiles of 256 rows
  const int b = gh >> 4, h = gh & 15;
  const int lr = lane & 15, lg = lane >> 4;

  const short* qp = (const short*)qkv_hm + (size_t)h * Mtot * 64;
  const short* kp = (const short*)qkv_hm + (size_t)(16 + h) * Mtot * 64;
  const short* vp = (const short*)qkv_hm + (size_t)(32 + h) * Mtot * 64;  // [64][M]

  const size_t qrow0 = (size_t)b * S + (size_t)qt * 256 + w * 32;
  bf16x8 qf[2][2];
#pragma unroll
  for (int mr = 0; mr < 2; ++mr)
#pragma unroll
    for (int kk = 0; kk < 2; ++kk)
      qf[mr][kk] = *(const bf16x8*)(qp + (qrow0 + mr * 16 + lr) * 64 + kk * 32 + lg * 8);

  f32x4 oacc[2][4] = {};
  float mrun[2][4], lrun[2][4];
#pragma unroll
  for (int mr = 0; mr < 2; ++mr)
#pragma unroll
    for (int r = 0; r < 4; ++r) { mrun[mr][r] = -1e30f; lrun[mr][r] = 0.f; }

  for (int kt = 0; kt < S / 128; ++kt) {
    const size_t krow0 = (size_t)b * S + (size_t)kt * 128;
    // ---- global loads (issue-and-consume: self-synchronizing; DO NOT prefetch) ----
    bf16x8 kreg[2], vreg[2];
#pragma unroll
    for (int i = 0; i < 2; ++i) {
      int slot = tid + 512 * i;  // 1024 16B-chunks: 128 keys x 8
      kreg[i] = *(const bf16x8*)(kp + krow0 * 64 + slot * 8);
    }
#pragma unroll
    for (int i = 0; i < 2; ++i) {
      int slot = tid + 512 * i;  // 1024 16B-chunks: 64 d-rows x 16
      int d = slot >> 4, ck = slot & 15;
      vreg[i] = *(const bf16x8*)(vp + (size_t)d * Mtot + krow0 + ck * 8);
    }
    // ---- LDS writes (both b128, swizzled) ----
#pragma unroll
    for (int i = 0; i < 2; ++i) {
      int slot = tid + 512 * i;
      int r = slot >> 3, c = slot & 7;
      *(bf16x8*)&lK[r * 64 + ((c ^ (r & 7)) << 3)] = kreg[i];
    }
#pragma unroll
    for (int i = 0; i < 2; ++i) {
      int slot = tid + 512 * i;
      int d = slot >> 4, ck = slot & 15;
      *(bf16x8*)&lVt[d * 128 + ((ck ^ (d & 15)) << 3)] = vreg[i];
    }
    __syncthreads();

    // ---- QK^T (1/sqrt(dk) pre-folded into Wq/bq) ----
    f32x4 sf[2][8] = {};
    __builtin_amdgcn_s_setprio(1);
#pragma unroll
    for (int kk = 0; kk < 2; ++kk) {
      bf16x8 bfr[8];
#pragma unroll
      for (int nb = 0; nb < 8; ++nb)
        bfr[nb] = *(const bf16x8*)&lK[(nb * 16 + lr) * 64 + (((kk * 4 + lg) ^ (lr & 7)) << 3)];
#pragma unroll
      for (int mr = 0; mr < 2; ++mr)
#pragma unroll
        for (int nb = 0; nb < 8; ++nb)
          sf[mr][nb] = __builtin_amdgcn_mfma_f32_16x16x32_bf16(qf[mr][kk], bfr[nb], sf[mr][nb], 0, 0, 0);
    }
    __builtin_amdgcn_s_setprio(0);

    // ---- row max over ALL keys; rescale oacc ----
    float ls[2][4];
#pragma unroll
    for (int mr = 0; mr < 2; ++mr) {
      float pm[4] = {-1e30f, -1e30f, -1e30f, -1e30f};
#pragma unroll
      for (int nb = 0; nb < 8; ++nb)
#pragma unroll
        for (int r = 0; r < 4; ++r) pm[r] = fmaxf(pm[r], sf[mr][nb][r]);
#pragma unroll
      for (int off = 1; off < 16; off <<= 1)
#pragma unroll
        for (int r = 0; r < 4; ++r) pm[r] = fmaxf(pm[r], __shfl_xor(pm[r], off));
#pragma unroll
      for (int r = 0; r < 4; ++r) {
        float nm = fmaxf(mrun[mr][r], pm[r]);
        float fac = __expf(mrun[mr][r] - nm);
        mrun[mr][r] = nm;
        lrun[mr][r] *= fac;
        ls[mr][r] = 0.f;
#pragma unroll
        for (int nd = 0; nd < 4; ++nd) oacc[mr][nd][r] *= fac;
      }
    }

    // ---- two key-halves: {exp + lP write} then {PV 2 kk}; PV MFMAs overlap next exps ----
#pragma unroll
    for (int half = 0; half < 2; ++half) {
#pragma unroll
      for (int mr = 0; mr < 2; ++mr)
#pragma unroll
        for (int nb = half * 4; nb < half * 4 + 4; ++nb)
#pragma unroll
          for (int r = 0; r < 4; ++r) {
            float p = __expf(sf[mr][nb][r] - mrun[mr][r]);
            ls[mr][r] += p;
            const int rr = w * 32 + mr * 16 + lg * 4 + r;
            const int c = (nb - half * 4) * 16 + lr;  // half-local column 0..63
            lP[rr * 64 + (((c >> 3) ^ (rr & 7)) << 3) + (c & 7)] = f2bf_s(p);
          }
      __builtin_amdgcn_s_setprio(1);
#pragma unroll
      for (int kkh = 0; kkh < 2; ++kkh) {
        const int kkg = half * 2 + kkh;
        bf16x8 pa[2], bv[4];
#pragma unroll
        for (int mr = 0; mr < 2; ++mr) {
          const int rr = w * 32 + mr * 16 + lr;
          pa[mr] = *(const bf16x8*)&lP[rr * 64 + (((kkh * 4 + lg) ^ (rr & 7)) << 3)];
        }
#pragma unroll
        for (int nd = 0; nd < 4; ++nd) {
          const int rd = nd * 16 + lr;
          bv[nd] = *(const bf16x8*)&lVt[rd * 128 + (((kkg * 4 + lg) ^ lr) << 3)];
        }
#pragma unroll
        for (int mr = 0; mr < 2; ++mr)
#pragma unroll
          for (int nd = 0; nd < 4; ++nd)
            oacc[mr][nd] = __builtin_amdgcn_mfma_f32_16x16x32_bf16(pa[mr], bv[nd], oacc[mr][nd], 0, 0, 0);
      }
      __builtin_amdgcn_s_setprio(0);
    }

    // ---- deferred sum reduce ----
#pragma unroll
    for (int mr = 0; mr < 2; ++mr) {
#pragma unroll
      for (int off = 1; off < 16; off <<= 1)
#pragma unroll
        for (int r = 0; r < 4; ++r) ls[mr][r] += __shfl_xor(ls[mr][r], off);
#pragma unroll
      for (int r = 0; r < 4; ++r) lrun[mr][r] += ls[mr][r];
    }
    __syncthreads();  // protect lK/lVt/lP overwrite next iteration
  }

  __hip_bfloat16* op = o_hm + (size_t)h * Mtot * 64;
#pragma unroll
  for (int mr = 0; mr < 2; ++mr) {
    float inv[4];
#pragma unroll
    for (int r = 0; r < 4; ++r) inv[r] = 1.0f / lrun[mr][r];
#pragma unroll
    for (int nd = 0; nd < 4; ++nd)
#pragma unroll
      for (int r = 0; r < 4; ++r) {
        size_t row = qrow0 + mr * 16 + lg * 4 + r;
        int col = nd * 16 + lr;
        op[row * 64 + col] = __float2bfloat16(oacc[mr][nd][r] * inv[r]);
      }
  }
}

// ---------------- fused residual + layernorm (fp32 in, fp32 + bf16 out) ----------------
// NY=2: y = y0 + y1 + bias (split-K partials).
template <int NY>
__global__ __launch_bounds__(256)
void residual_ln(const float* __restrict__ xin, const float* __restrict__ y0,
                 const float* __restrict__ y1, const float* __restrict__ bias,
                 const float* __restrict__ g, const float* __restrict__ beta,
                 float* __restrict__ xout, __hip_bfloat16* __restrict__ xb) {
  const int D = 1024;
  const int row = blockIdx.x, t = threadIdx.x;
  const float4 xv = ((const float4*)(xin + (size_t)row * D))[t];
  float4 yv = ((const float4*)(y0 + (size_t)row * D))[t];
  if (NY == 2) {
    const float4 y1v = ((const float4*)(y1 + (size_t)row * D))[t];
    const float4 bv2 = ((const float4*)bias)[t];
    yv.x += y1v.x + bv2.x; yv.y += y1v.y + bv2.y;
    yv.z += y1v.z + bv2.z; yv.w += y1v.w + bv2.w;
  }
  float va0 = xv.x + yv.x, va1 = xv.y + yv.y, va2 = xv.z + yv.z, va3 = xv.w + yv.w;
  __shared__ float red[4];
  float s = va0 + va1 + va2 + va3;
#pragma unroll
  for (int off = 32; off; off >>= 1) s += __shfl_xor(s, off);
  if ((t & 63) == 0) red[t >> 6] = s;
  __syncthreads();
  const float mu = (red[0] + red[1] + red[2] + red[3]) * (1.0f / D);
  __syncthreads();
  float d0 = va0 - mu, d1 = va1 - mu, d2 = va2 - mu, d3 = va3 - mu;
  float ss = d0 * d0 + d1 * d1 + d2 * d2 + d3 * d3;
#pragma unroll
  for (int off = 32; off; off >>= 1) ss += __shfl_xor(ss, off);
  if ((t & 63) == 0) red[t >> 6] = ss;
  __syncthreads();
  const float var = (red[0] + red[1] + red[2] + red[3]) * (1.0f / D);
  const float rstd = rsqrtf(var + 1e-5f);
  const float4 gv = ((const float4*)g)[t];
  const float4 bv = ((const float4*)beta)[t];
  float o0 = d0 * rstd * gv.x + bv.x;
  float o1 = d1 * rstd * gv.y + bv.y;
  float o2 = d2 * rstd * gv.z + bv.z;
  float o3 = d3 * rstd * gv.w + bv.w;
  ((float4*)(xout + (size_t)row * D))[t] = make_float4(o0, o1, o2, o3);
  __hip_bfloat16* ob = xb + (size_t)row * D + (size_t)t * 4;
  ob[0] = __float2bfloat16(o0); ob[1] = __float2bfloat16(o1);
  ob[2] = __float2bfloat16(o2); ob[3] = __float2bfloat16(o3);
}

// ---------------- launcher ----------------
extern "C" void kernel_launch(void* const* d_in, const int* in_sizes, int n_in,
                              void* d_out, int out_size, void* d_ws, size_t ws_size,
                              hipStream_t stream) {
  const int L = 6, D = 1024, DFF = 4096, B = 2, S = 2048, M = B * S;
  const float* x_in = (const float*)d_in[0];
  const float* Wq = (const float*)d_in[1];
  const float* bq = (const float*)d_in[2];
  const float* Wk = (const float*)d_in[3];
  const float* bk = (const float*)d_in[4];
  const float* Wv = (const float*)d_in[5];
  const float* bvp = (const float*)d_in[6];
  const float* Wo = (const float*)d_in[7];
  const float* bo = (const float*)d_in[8];
  const float* g1 = (const float*)d_in[9];
  const float* be1 = (const float*)d_in[10];
  const float* W1 = (const float*)d_in[11];
  const float* b1 = (const float*)d_in[12];
  const float* W2 = (const float*)d_in[13];
  const float* b2 = (const float*)d_in[14];
  const float* g2 = (const float*)d_in[15];
  const float* be2 = (const float*)d_in[16];

  char* base = (char*)d_ws;
  size_t off = 0;
  auto carve = [&](size_t bytes) {
    char* p = base + off;
    off += (bytes + 255) & ~(size_t)255;
    return p;
  };
  const size_t LAYER_ELEMS = 4 * (size_t)D * D + 2 * (size_t)D * DFF;  // 12,582,912
  __hip_bfloat16* wT = (__hip_bfloat16*)carve(L * LAYER_ELEMS * 2);
  float* bqkv = (float*)carve((size_t)L * 3 * D * 4);
  float* xf = (float*)carve((size_t)M * D * 4);
  __hip_bfloat16* xb = (__hip_bfloat16*)carve((size_t)M * D * 2);
  __hip_bfloat16* qkvb = (__hip_bfloat16*)carve((size_t)M * 3 * D * 2);  // q,k: [h][M][64]; v: [h][64][M]; 24MB
  __hip_bfloat16* ob = (__hip_bfloat16*)carve((size_t)M * D * 2);        // head-major [16][M][64], 8MB
  __hip_bfloat16* hb = (__hip_bfloat16*)carve((size_t)M * DFF * 2);      // 32MB
  float* yf = (float*)carve((size_t)M * D * 4);                          // 16MB
  if (off > ws_size) return;
  // split-K partials: TWO DISJOINT dead regions, neither aliasing the GEMM's A input.
  float* p0 = (float*)qkvb;
  float* p1 = yf;

  dim3 blk(256);
  const float qscale = 0.03125f;  // 1/sqrt(1024) = 2^-5, exact in bf16
  transpose_to_bf16<<<dim3(D / 32, D / 32, L), blk, 0, stream>>>(
      Wq, wT + 0 * (size_t)D * D, D, D, (size_t)D * D, LAYER_ELEMS, qscale);
  transpose_to_bf16<<<dim3(D / 32, D / 32, L), blk, 0, stream>>>(
      Wk, wT + 1 * (size_t)D * D, D, D, (size_t)D * D, LAYER_ELEMS, 1.0f);
  transpose_to_bf16<<<dim3(D / 32, D / 32, L), blk, 0, stream>>>(
      Wv, wT + 2 * (size_t)D * D, D, D, (size_t)D * D, LAYER_ELEMS, 1.0f);
  transpose_to_bf16<<<dim3(D / 32, D / 32, L), blk, 0, stream>>>(
      Wo, wT + 3 * (size_t)D * D, D, D, (size_t)D * D, LAYER_ELEMS, 1.0f);
  transpose_to_bf16<<<dim3(DFF / 32, D / 32, L), blk, 0, stream>>>(
      W1, wT + 4 * (size_t)D * D, D, DFF, (size_t)D * DFF, LAYER_ELEMS, 1.0f);
  transpose_to_bf16<<<dim3(D / 32, DFF / 32, L), blk, 0, stream>>>(
      W2, wT + 4 * (size_t)D * D + (size_t)D * DFF, DFF, D, (size_t)D * DFF, LAYER_ELEMS, 1.0f);
  pack_qkv_bias<<<dim3(L * 3 * D / 256), blk, 0, stream>>>(bq, bk, bvp, bqkv, qscale);
  init_x<<<dim3(M * D / 4 / 256), blk, 0, stream>>>(x_in, xf, xb, M * D / 4);

  for (int l = 0; l < L; ++l) {
    const __hip_bfloat16* WqkvT = wT + (size_t)l * LAYER_ELEMS;  // rows: [Wq^T|Wk^T|Wv^T]
    const __hip_bfloat16* WoT = WqkvT + 3 * (size_t)D * D;
    const __hip_bfloat16* W1T = WoT + (size_t)D * D;
    const __hip_bfloat16* W2T = W1T + (size_t)D * DFF;
    gemm_bt<true, false, false, true><<<dim3(3 * D / 128, M / 128), blk, 0, stream>>>(
        xb, WqkvT, bqkv + (size_t)l * 3 * D, qkvb, M, 3 * D, D);
    attn_kernel<<<dim3(256), dim3(512), 0, stream>>>(qkvb, ob, M);
    // O-proj: split-K x2; partials p0 (=qkvb, dead) + p1 (=yf); LN1 sums (+bias bo)
    gemm_sk<true><<<dim3(D / 128, M / 128, 2), blk, 0, stream>>>(
        ob, WoT, p0, p1, M, D, D);
    residual_ln<2><<<dim3(M), blk, 0, stream>>>(
        xf, p0, p1, bo + (size_t)l * D,
        g1 + (size_t)l * D, be1 + (size_t)l * D, xf, xb);
    gemm_bt<true, true, false, false><<<dim3(DFF / 128, M / 128), blk, 0, stream>>>(
        xb, W1T, b1 + (size_t)l * DFF, hb, M, DFF, D);
    // FFN2: split-K x2; partials p0 + p1; LN2 sums (+bias b2)
    gemm_sk<false><<<dim3(D / 128, M / 128, 2), blk, 0, stream>>>(
        hb, W2T, p0, p1, M, D, DFF);
    residual_ln<2><<<dim3(M), blk, 0, stream>>>(
        xf, p0, p1, b2 + (size_t)l * D,
        g2 + (size_t)l * D, be2 + (size_t)l * D, xf, xb);
  }

  hipMemcpyAsync(d_out, xf, (size_t)M * D * sizeof(float), hipMemcpyDeviceToDevice, stream);
}

// Round 19
// 1669.118 us; speedup vs baseline: 1.9616x; 1.0262x over previous
//
#include <hip/hip_runtime.h>
#include <hip/hip_bf16.h>

#define DEV __device__ __forceinline__

typedef __attribute__((ext_vector_type(8))) __bf16 bf16x8;
typedef __attribute__((ext_vector_type(4))) float f32x4;
typedef __attribute__((ext_vector_type(4))) short short4v;

DEV void gload_lds16(const void* g, void* l) {
  __builtin_amdgcn_global_load_lds((const __attribute__((address_space(1))) void*)g,
                                   (__attribute__((address_space(3))) void*)l, 16, 0, 0);
}

DEV short f2bf_s(float f) {
  __hip_bfloat16 h = __float2bfloat16(f);
  return __builtin_bit_cast(short, h);
}

DEV float bf2f(short s) {
  unsigned int u = ((unsigned int)(unsigned short)s) << 16;
  return __builtin_bit_cast(float, u);
}

// ---------------- weight prep: fp32 [L][K][N] -> bf16 [L][N][K] (optionally scaled) ------
__global__ __launch_bounds__(256)
void transpose_to_bf16(const float* __restrict__ src, __hip_bfloat16* __restrict__ dst,
                       int K, int N, size_t srcLayerStride, size_t dstLayerStride,
                       float scale) {
  __shared__ float t[32][33];
  const int n0 = blockIdx.x * 32, k0 = blockIdx.y * 32;
  const float* s = src + (size_t)blockIdx.z * srcLayerStride;
  __hip_bfloat16* d = dst + (size_t)blockIdx.z * dstLayerStride;
  const int tx = threadIdx.x & 31, ty = threadIdx.x >> 5;  // 32 x 8
#pragma unroll
  for (int j = 0; j < 4; ++j)
    t[ty + j * 8][tx] = s[(size_t)(k0 + ty + j * 8) * N + n0 + tx];
  __syncthreads();
#pragma unroll
  for (int j = 0; j < 4; ++j)
    d[(size_t)(n0 + ty + j * 8) * K + k0 + tx] = __float2bfloat16(t[tx][ty + j * 8] * scale);
}

// ---------------- pack QKV biases: [L][3072] = [bq*s | bk | bv] ----------------
__global__ __launch_bounds__(256)
void pack_qkv_bias(const float* __restrict__ bq, const float* __restrict__ bk,
                   const float* __restrict__ bv, float* __restrict__ out, float qs) {
  int idx = blockIdx.x * 256 + threadIdx.x;  // L*3072 total
  int l = idx / 3072, j = idx % 3072;
  float v;
  if (j < 1024) v = bq[l * 1024 + j] * qs;
  else if (j < 2048) v = bk[l * 1024 + j - 1024];
  else v = bv[l * 1024 + j - 2048];
  out[idx] = v;
}

// ---------------- x init: copy fp32 + bf16 shadow ----------------
__global__ __launch_bounds__(256)
void init_x(const float* __restrict__ xin, float* __restrict__ xf,
            __hip_bfloat16* __restrict__ xb, int n4) {
  int i = blockIdx.x * 256 + threadIdx.x;
  if (i < n4) {
    float4 v = ((const float4*)xin)[i];
    ((float4*)xf)[i] = v;
    __hip_bfloat16* o = xb + (size_t)i * 4;
    o[0] = __float2bfloat16(v.x); o[1] = __float2bfloat16(v.y);
    o[2] = __float2bfloat16(v.z); o[3] = __float2bfloat16(v.w);
  }
}

// ---------------- GEMM (single-buffer, m97 structure): multi-block/CU grids ----------------
// AHM: A physically head-major [K/64][M][64]
// CHM: C physically head-major. For the QKV GEMM (CHM=true):
//   cols <  2048 (Q,K thirds): [col/64][M][64]   (row-major per head)
//   cols >= 2048 (V third):    [col/64][64][M]   (COLUMN-major per head) — attn then
//   stages V with dense b128 loads (transpose done for free in this epilogue).
template <bool OUT_BF16, bool RELU, bool AHM, bool CHM>
__global__ __launch_bounds__(256, 2)
void gemm_bt(const __hip_bfloat16* __restrict__ A, const __hip_bfloat16* __restrict__ Bt,
             const float* __restrict__ bias, void* __restrict__ Cout,
             int M, int N, int K) {
  __shared__ __align__(16) short lA[128 * 64];
  __shared__ __align__(16) short lB[128 * 64];
  const int tid = threadIdx.x;
  const int lane = tid & 63, w = tid >> 6;
  const int m0 = blockIdx.y * 128, n0 = blockIdx.x * 128;
  const int wr = w >> 1, wc = w & 1;
  const int lr = lane & 15, lg = lane >> 4;
  const int srow = lane >> 3, scol = (lane & 7) * 8;
  f32x4 acc[4][4] = {};
  const short* Asrc = (const short*)A;
  const short* Bsrc = (const short*)Bt;
  for (int k0 = 0; k0 < K; k0 += 64) {
#pragma unroll
    for (int i = 0; i < 4; ++i) {
      int s = w * 4 + i;
      const short* ap;
      if (AHM)
        ap = Asrc + ((size_t)(k0 >> 6) * M + (m0 + s * 8 + srow)) * 64 + scol;
      else
        ap = Asrc + (size_t)(m0 + s * 8 + srow) * K + k0 + scol;
      gload_lds16(ap, lA + s * 512);
    }
#pragma unroll
    for (int i = 0; i < 4; ++i) {
      int s = w * 4 + i;
      gload_lds16(Bsrc + (size_t)(n0 + s * 8 + srow) * K + k0 + scol, lB + s * 512);
    }
    __syncthreads();
#pragma unroll
    for (int kk = 0; kk < 2; ++kk) {
      const int lk = kk * 32 + lg * 8;
      bf16x8 af[4], bfr[4];
#pragma unroll
      for (int mr = 0; mr < 4; ++mr)
        af[mr] = *(const bf16x8*)&lA[(wr * 64 + mr * 16 + lr) * 64 + lk];
#pragma unroll
      for (int nc = 0; nc < 4; ++nc)
        bfr[nc] = *(const bf16x8*)&lB[(wc * 64 + nc * 16 + lr) * 64 + lk];
#pragma unroll
      for (int mr = 0; mr < 4; ++mr)
#pragma unroll
        for (int nc = 0; nc < 4; ++nc)
          acc[mr][nc] = __builtin_amdgcn_mfma_f32_16x16x32_bf16(af[mr], bfr[nc], acc[mr][nc], 0, 0, 0);
    }
    __syncthreads();
  }
  if (CHM && n0 >= 2048) {
    // V third: column-major per head. 4 consecutive rows pack into one 8B store.
#pragma unroll
    for (int mr = 0; mr < 4; ++mr)
#pragma unroll
      for (int nc = 0; nc < 4; ++nc) {
        const int col = n0 + wc * 64 + nc * 16 + lr;
        const float bv = bias[col];
        const int row0 = m0 + wr * 64 + mr * 16 + lg * 4;
        short4v pack;
#pragma unroll
        for (int r = 0; r < 4; ++r) pack[r] = f2bf_s(acc[mr][nc][r] + bv);
        *(short4v*)((short*)Cout + ((size_t)(col >> 6) * 64 + (col & 63)) * M + row0) = pack;
      }
    return;
  }
#pragma unroll
  for (int mr = 0; mr < 4; ++mr)
#pragma unroll
    for (int nc = 0; nc < 4; ++nc) {
      const int col = n0 + wc * 64 + nc * 16 + lr;
      const float bv = bias[col];
#pragma unroll
      for (int r = 0; r < 4; ++r) {
        const int row = m0 + wr * 64 + mr * 16 + lg * 4 + r;
        float vv = acc[mr][nc][r] + bv;
        if (RELU) vv = fmaxf(vv, 0.f);
        size_t cidx;
        if (CHM) cidx = ((size_t)(col >> 6) * M + row) * 64 + (col & 63);
        else cidx = (size_t)row * N + col;
        if (OUT_BF16)
          ((__hip_bfloat16*)Cout)[cidx] = __float2bfloat16(vv);
        else
          ((float*)Cout)[cidx] = vv;
      }
    }
}

// ---------------- split-K GEMM (2-phase dbuf, z = K-half; no bias) ----------------
// For N=1024 GEMMs (O-proj AHM=true, FFN2 AHM=false). 512 blocks = 2/CU.
// Partials written as BF16 (halves partial traffic; abs err ~1e-3 on O(0.6) values,
// absorbed by LN — threshold headroom 3x). TWO DISJOINT dead buffers C0/C1
// (r14 lesson: never alias A).
template <bool AHM>
__global__ __launch_bounds__(256, 2)
void gemm_sk(const __hip_bfloat16* __restrict__ A, const __hip_bfloat16* __restrict__ Bt,
             __hip_bfloat16* __restrict__ C0, __hip_bfloat16* __restrict__ C1,
             int M, int N, int K) {
  __shared__ __align__(16) short lA[2][128 * 64];
  __shared__ __align__(16) short lB[2][128 * 64];
  const int tid = threadIdx.x;
  const int lane = tid & 63, w = tid >> 6;
  const int m0 = blockIdx.y * 128, n0 = blockIdx.x * 128;
  const int z = blockIdx.z;
  const int Ksub = K >> 1, kbase = z * Ksub;
  const int wr = w >> 1, wc = w & 1;
  const int lr = lane & 15, lg = lane >> 4;
  const int srow = lane >> 3, scol = (lane & 7) * 8;
  f32x4 acc[4][4] = {};
  const short* Asrc = (const short*)A;
  const short* Bsrc = (const short*)Bt;
  const int KT = Ksub >> 6;

  auto stage = [&](int buf, int t) {
    const int kc = kbase + t * 64;
#pragma unroll
    for (int i = 0; i < 4; ++i) {
      int s = w * 4 + i;
      const short* ap;
      if (AHM)
        ap = Asrc + ((size_t)(kc >> 6) * M + (m0 + s * 8 + srow)) * 64 + scol;
      else
        ap = Asrc + (size_t)(m0 + s * 8 + srow) * K + kc + scol;
      gload_lds16(ap, &lA[buf][s * 512]);
      gload_lds16(Bsrc + (size_t)(n0 + s * 8 + srow) * K + kc + scol, &lB[buf][s * 512]);
    }
  };

  stage(0, 0);
  __syncthreads();

  int cur = 0;
  for (int t = 0; t < KT; ++t) {
    if (t + 1 < KT) stage(cur ^ 1, t + 1);
    const short* cA = lA[cur];
    const short* cB = lB[cur];
#pragma unroll
    for (int kk = 0; kk < 2; ++kk) {
      const int lk = kk * 32 + lg * 8;
      bf16x8 af[4], bfr[4];
#pragma unroll
      for (int mr = 0; mr < 4; ++mr)
        af[mr] = *(const bf16x8*)&cA[(wr * 64 + mr * 16 + lr) * 64 + lk];
#pragma unroll
      for (int nc = 0; nc < 4; ++nc)
        bfr[nc] = *(const bf16x8*)&cB[(wc * 64 + nc * 16 + lr) * 64 + lk];
      __builtin_amdgcn_s_setprio(1);
#pragma unroll
      for (int mr = 0; mr < 4; ++mr)
#pragma unroll
        for (int nc = 0; nc < 4; ++nc)
          acc[mr][nc] = __builtin_amdgcn_mfma_f32_16x16x32_bf16(af[mr], bfr[nc], acc[mr][nc], 0, 0, 0);
      __builtin_amdgcn_s_setprio(0);
    }
    __syncthreads();
    cur ^= 1;
  }

  __hip_bfloat16* Cz = z ? C1 : C0;
#pragma unroll
  for (int mr = 0; mr < 4; ++mr)
#pragma unroll
    for (int nc = 0; nc < 4; ++nc) {
      const int col = n0 + wc * 64 + nc * 16 + lr;
#pragma unroll
      for (int r = 0; r < 4; ++r) {
        const int row = m0 + wr * 64 + mr * 16 + lg * 4 + r;
        Cz[(size_t)row * N + col] = __float2bfloat16(acc[mr][nc][r]);
      }
    }
}

// ---------------- flash attention: Q,K head-major [.][M][64]; V COLUMN-major [.][64][M] ---
// EXACT round-16 version (measured 87us): 4-wave blocks, b128 K+V staging, lP [128][64]
// wave-private, two-half exp||PV interleave, XCD head-pinning.
// Loads issue-and-consume (DO NOT prefetch — r5/r9 13x overfetch).
__global__ __launch_bounds__(256, 2)
void attn_kernel(const __hip_bfloat16* __restrict__ qkv_hm, __hip_bfloat16* __restrict__ o_hm,
                 int Mtot) {
  const int S = 2048;
  __shared__ __align__(16) short lK[128 * 64];    // [key][64],  swz chunk ^ (key&7)
  __shared__ __align__(16) short lVt[64 * 128];   // [d][128],   swz chunk ^ (d&15)
  __shared__ __align__(16) short lP[128 * 64];    // [qr][64],   swz chunk ^ (qr&7); wave-private rows
  const int tid = threadIdx.x, lane = tid & 63, w = tid >> 6;
  const int bid = blockIdx.x;
  const int xcd = bid & 7, u = bid >> 3;
  const int gh = (u >> 4) * 8 + xcd;   // 0..31 = (b,h)
  const int qt = u & 15;
  const int b = gh >> 4, h = gh & 15;
  const int lr = lane & 15, lg = lane >> 4;

  const short* qp = (const short*)qkv_hm + (size_t)h * Mtot * 64;
  const short* kp = (const short*)qkv_hm + (size_t)(16 + h) * Mtot * 64;
  const short* vp = (const short*)qkv_hm + (size_t)(32 + h) * Mtot * 64;  // [64][M]

  const size_t qrow0 = (size_t)b * S + (size_t)qt * 128 + w * 32;
  bf16x8 qf[2][2];
#pragma unroll
  for (int mr = 0; mr < 2; ++mr)
#pragma unroll
    for (int kk = 0; kk < 2; ++kk)
      qf[mr][kk] = *(const bf16x8*)(qp + (qrow0 + mr * 16 + lr) * 64 + kk * 32 + lg * 8);

  f32x4 oacc[2][4] = {};
  float mrun[2][4], lrun[2][4];
#pragma unroll
  for (int mr = 0; mr < 2; ++mr)
#pragma unroll
    for (int r = 0; r < 4; ++r) { mrun[mr][r] = -1e30f; lrun[mr][r] = 0.f; }

  for (int kt = 0; kt < S / 128; ++kt) {
    const size_t krow0 = (size_t)b * S + (size_t)kt * 128;
    // ---- global loads (issue-and-consume: self-synchronizing; DO NOT prefetch) ----
    bf16x8 kreg[4], vreg[4];
#pragma unroll
    for (int i = 0; i < 4; ++i) {
      int slot = tid + 256 * i;  // 1024 16B-chunks: 128 keys x 8
      kreg[i] = *(const bf16x8*)(kp + krow0 * 64 + slot * 8);
    }
#pragma unroll
    for (int i = 0; i < 4; ++i) {
      int slot = tid + 256 * i;  // 1024 16B-chunks: 64 d-rows x 16
      int d = slot >> 4, ck = slot & 15;
      vreg[i] = *(const bf16x8*)(vp + (size_t)d * Mtot + krow0 + ck * 8);
    }
    // ---- LDS writes (both b128, swizzled) ----
#pragma unroll
    for (int i = 0; i < 4; ++i) {
      int slot = tid + 256 * i;
      int r = slot >> 3, c = slot & 7;
      *(bf16x8*)&lK[r * 64 + ((c ^ (r & 7)) << 3)] = kreg[i];
    }
#pragma unroll
    for (int i = 0; i < 4; ++i) {
      int slot = tid + 256 * i;
      int d = slot >> 4, ck = slot & 15;
      *(bf16x8*)&lVt[d * 128 + ((ck ^ (d & 15)) << 3)] = vreg[i];
    }
    __syncthreads();

    // ---- QK^T (1/sqrt(dk) pre-folded into Wq/bq) ----
    f32x4 sf[2][8] = {};
    __builtin_amdgcn_s_setprio(1);
#pragma unroll
    for (int kk = 0; kk < 2; ++kk) {
      bf16x8 bfr[8];
#pragma unroll
      for (int nb = 0; nb < 8; ++nb)
        bfr[nb] = *(const bf16x8*)&lK[(nb * 16 + lr) * 64 + (((kk * 4 + lg) ^ (lr & 7)) << 3)];
#pragma unroll
      for (int mr = 0; mr < 2; ++mr)
#pragma unroll
        for (int nb = 0; nb < 8; ++nb)
          sf[mr][nb] = __builtin_amdgcn_mfma_f32_16x16x32_bf16(qf[mr][kk], bfr[nb], sf[mr][nb], 0, 0, 0);
    }
    __builtin_amdgcn_s_setprio(0);

    // ---- row max over ALL keys; rescale oacc ----
    float ls[2][4];
#pragma unroll
    for (int mr = 0; mr < 2; ++mr) {
      float pm[4] = {-1e30f, -1e30f, -1e30f, -1e30f};
#pragma unroll
      for (int nb = 0; nb < 8; ++nb)
#pragma unroll
        for (int r = 0; r < 4; ++r) pm[r] = fmaxf(pm[r], sf[mr][nb][r]);
#pragma unroll
      for (int off = 1; off < 16; off <<= 1)
#pragma unroll
        for (int r = 0; r < 4; ++r) pm[r] = fmaxf(pm[r], __shfl_xor(pm[r], off));
#pragma unroll
      for (int r = 0; r < 4; ++r) {
        float nm = fmaxf(mrun[mr][r], pm[r]);
        float fac = __expf(mrun[mr][r] - nm);
        mrun[mr][r] = nm;
        lrun[mr][r] *= fac;
        ls[mr][r] = 0.f;
#pragma unroll
        for (int nd = 0; nd < 4; ++nd) oacc[mr][nd][r] *= fac;
      }
    }

    // ---- two key-halves: {exp + lP write} then {PV 2 kk}; PV MFMAs overlap next exps ----
#pragma unroll
    for (int half = 0; half < 2; ++half) {
#pragma unroll
      for (int mr = 0; mr < 2; ++mr)
#pragma unroll
        for (int nb = half * 4; nb < half * 4 + 4; ++nb)
#pragma unroll
          for (int r = 0; r < 4; ++r) {
            float p = __expf(sf[mr][nb][r] - mrun[mr][r]);
            ls[mr][r] += p;
            const int rr = w * 32 + mr * 16 + lg * 4 + r;
            const int c = (nb - half * 4) * 16 + lr;  // half-local column 0..63
            lP[rr * 64 + (((c >> 3) ^ (rr & 7)) << 3) + (c & 7)] = f2bf_s(p);
          }
      __builtin_amdgcn_s_setprio(1);
#pragma unroll
      for (int kkh = 0; kkh < 2; ++kkh) {
        const int kkg = half * 2 + kkh;
        bf16x8 pa[2], bv[4];
#pragma unroll
        for (int mr = 0; mr < 2; ++mr) {
          const int rr = w * 32 + mr * 16 + lr;
          pa[mr] = *(const bf16x8*)&lP[rr * 64 + (((kkh * 4 + lg) ^ (rr & 7)) << 3)];
        }
#pragma unroll
        for (int nd = 0; nd < 4; ++nd) {
          const int rd = nd * 16 + lr;
          bv[nd] = *(const bf16x8*)&lVt[rd * 128 + (((kkg * 4 + lg) ^ lr) << 3)];
        }
#pragma unroll
        for (int mr = 0; mr < 2; ++mr)
#pragma unroll
          for (int nd = 0; nd < 4; ++nd)
            oacc[mr][nd] = __builtin_amdgcn_mfma_f32_16x16x32_bf16(pa[mr], bv[nd], oacc[mr][nd], 0, 0, 0);
      }
      __builtin_amdgcn_s_setprio(0);
    }

    // ---- deferred sum reduce ----
#pragma unroll
    for (int mr = 0; mr < 2; ++mr) {
#pragma unroll
      for (int off = 1; off < 16; off <<= 1)
#pragma unroll
        for (int r = 0; r < 4; ++r) ls[mr][r] += __shfl_xor(ls[mr][r], off);
#pragma unroll
      for (int r = 0; r < 4; ++r) lrun[mr][r] += ls[mr][r];
    }
    __syncthreads();  // protect lK/lVt/lP overwrite next iteration
  }

  __hip_bfloat16* op = o_hm + (size_t)h * Mtot * 64;
#pragma unroll
  for (int mr = 0; mr < 2; ++mr) {
    float inv[4];
#pragma unroll
    for (int r = 0; r < 4; ++r) inv[r] = 1.0f / lrun[mr][r];
#pragma unroll
    for (int nd = 0; nd < 4; ++nd)
#pragma unroll
      for (int r = 0; r < 4; ++r) {
        size_t row = qrow0 + mr * 16 + lg * 4 + r;
        int col = nd * 16 + lr;
        op[row * 64 + col] = __float2bfloat16(oacc[mr][nd][r] * inv[r]);
      }
  }
}

// ---------------- fused residual + layernorm (bf16 split-K partials in) ----------------
// y = y0 + y1 + bias, where y0/y1 are bf16 partials from gemm_sk.
__global__ __launch_bounds__(256)
void residual_ln(const float* __restrict__ xin, const __hip_bfloat16* __restrict__ y0,
                 const __hip_bfloat16* __restrict__ y1, const float* __restrict__ bias,
                 const float* __restrict__ g, const float* __restrict__ beta,
                 float* __restrict__ xout, __hip_bfloat16* __restrict__ xb) {
  const int D = 1024;
  const int row = blockIdx.x, t = threadIdx.x;
  const float4 xv = ((const float4*)(xin + (size_t)row * D))[t];
  const short4v y0v = ((const short4v*)((const short*)y0 + (size_t)row * D))[t];
  const short4v y1v = ((const short4v*)((const short*)y1 + (size_t)row * D))[t];
  const float4 bv2 = ((const float4*)bias)[t];
  float va0 = xv.x + bf2f(y0v[0]) + bf2f(y1v[0]) + bv2.x;
  float va1 = xv.y + bf2f(y0v[1]) + bf2f(y1v[1]) + bv2.y;
  float va2 = xv.z + bf2f(y0v[2]) + bf2f(y1v[2]) + bv2.z;
  float va3 = xv.w + bf2f(y0v[3]) + bf2f(y1v[3]) + bv2.w;
  __shared__ float red[4];
  float s = va0 + va1 + va2 + va3;
#pragma unroll
  for (int off = 32; off; off >>= 1) s += __shfl_xor(s, off);
  if ((t & 63) == 0) red[t >> 6] = s;
  __syncthreads();
  const float mu = (red[0] + red[1] + red[2] + red[3]) * (1.0f / D);
  __syncthreads();
  float d0 = va0 - mu, d1 = va1 - mu, d2 = va2 - mu, d3 = va3 - mu;
  float ss = d0 * d0 + d1 * d1 + d2 * d2 + d3 * d3;
#pragma unroll
  for (int off = 32; off; off >>= 1) ss += __shfl_xor(ss, off);
  if ((t & 63) == 0) red[t >> 6] = ss;
  __syncthreads();
  const float var = (red[0] + red[1] + red[2] + red[3]) * (1.0f / D);
  const float rstd = rsqrtf(var + 1e-5f);
  const float4 gv = ((const float4*)g)[t];
  const float4 bv = ((const float4*)beta)[t];
  float o0 = d0 * rstd * gv.x + bv.x;
  float o1 = d1 * rstd * gv.y + bv.y;
  float o2 = d2 * rstd * gv.z + bv.z;
  float o3 = d3 * rstd * gv.w + bv.w;
  ((float4*)(xout + (size_t)row * D))[t] = make_float4(o0, o1, o2, o3);
  __hip_bfloat16* ob = xb + (size_t)row * D + (size_t)t * 4;
  ob[0] = __float2bfloat16(o0); ob[1] = __float2bfloat16(o1);
  ob[2] = __float2bfloat16(o2); ob[3] = __float2bfloat16(o3);
}

// ---------------- launcher ----------------
extern "C" void kernel_launch(void* const* d_in, const int* in_sizes, int n_in,
                              void* d_out, int out_size, void* d_ws, size_t ws_size,
                              hipStream_t stream) {
  const int L = 6, D = 1024, DFF = 4096, B = 2, S = 2048, M = B * S;
  const float* x_in = (const float*)d_in[0];
  const float* Wq = (const float*)d_in[1];
  const float* bq = (const float*)d_in[2];
  const float* Wk = (const float*)d_in[3];
  const float* bk = (const float*)d_in[4];
  const float* Wv = (const float*)d_in[5];
  const float* bvp = (const float*)d_in[6];
  const float* Wo = (const float*)d_in[7];
  const float* bo = (const float*)d_in[8];
  const float* g1 = (const float*)d_in[9];
  const float* be1 = (const float*)d_in[10];
  const float* W1 = (const float*)d_in[11];
  const float* b1 = (const float*)d_in[12];
  const float* W2 = (const float*)d_in[13];
  const float* b2 = (const float*)d_in[14];
  const float* g2 = (const float*)d_in[15];
  const float* be2 = (const float*)d_in[16];

  char* base = (char*)d_ws;
  size_t off = 0;
  auto carve = [&](size_t bytes) {
    char* p = base + off;
    off += (bytes + 255) & ~(size_t)255;
    return p;
  };
  const size_t LAYER_ELEMS = 4 * (size_t)D * D + 2 * (size_t)D * DFF;  // 12,582,912
  __hip_bfloat16* wT = (__hip_bfloat16*)carve(L * LAYER_ELEMS * 2);
  float* bqkv = (float*)carve((size_t)L * 3 * D * 4);
  float* xf = (float*)carve((size_t)M * D * 4);
  __hip_bfloat16* xb = (__hip_bfloat16*)carve((size_t)M * D * 2);
  __hip_bfloat16* qkvb = (__hip_bfloat16*)carve((size_t)M * 3 * D * 2);  // q,k: [h][M][64]; v: [h][64][M]; 24MB
  __hip_bfloat16* ob = (__hip_bfloat16*)carve((size_t)M * D * 2);        // head-major [16][M][64], 8MB
  __hip_bfloat16* hb = (__hip_bfloat16*)carve((size_t)M * DFF * 2);      // 32MB
  float* yf = (float*)carve((size_t)M * D * 4);                          // 16MB
  if (off > ws_size) return;
  // split-K partials (bf16, 8MB each): TWO DISJOINT dead regions, never aliasing
  // the GEMM's A input (r14 lesson). p0 = qkvb (24MB, dead after attn),
  // p1 = yf (16MB, dead).
  __hip_bfloat16* p0 = qkvb;
  __hip_bfloat16* p1 = (__hip_bfloat16*)yf;

  dim3 blk(256);
  const float qscale = 0.03125f;  // 1/sqrt(1024) = 2^-5, exact in bf16
  transpose_to_bf16<<<dim3(D / 32, D / 32, L), blk, 0, stream>>>(
      Wq, wT + 0 * (size_t)D * D, D, D, (size_t)D * D, LAYER_ELEMS, qscale);
  transpose_to_bf16<<<dim3(D / 32, D / 32, L), blk, 0, stream>>>(
      Wk, wT + 1 * (size_t)D * D, D, D, (size_t)D * D, LAYER_ELEMS, 1.0f);
  transpose_to_bf16<<<dim3(D / 32, D / 32, L), blk, 0, stream>>>(
      Wv, wT + 2 * (size_t)D * D, D, D, (size_t)D * D, LAYER_ELEMS, 1.0f);
  transpose_to_bf16<<<dim3(D / 32, D / 32, L), blk, 0, stream>>>(
      Wo, wT + 3 * (size_t)D * D, D, D, (size_t)D * D, LAYER_ELEMS, 1.0f);
  transpose_to_bf16<<<dim3(DFF / 32, D / 32, L), blk, 0, stream>>>(
      W1, wT + 4 * (size_t)D * D, D, DFF, (size_t)D * DFF, LAYER_ELEMS, 1.0f);
  transpose_to_bf16<<<dim3(D / 32, DFF / 32, L), blk, 0, stream>>>(
      W2, wT + 4 * (size_t)D * D + (size_t)D * DFF, DFF, D, (size_t)D * DFF, LAYER_ELEMS, 1.0f);
  pack_qkv_bias<<<dim3(L * 3 * D / 256), blk, 0, stream>>>(bq, bk, bvp, bqkv, qscale);
  init_x<<<dim3(M * D / 4 / 256), blk, 0, stream>>>(x_in, xf, xb, M * D / 4);

  for (int l = 0; l < L; ++l) {
    const __hip_bfloat16* WqkvT = wT + (size_t)l * LAYER_ELEMS;  // rows: [Wq^T|Wk^T|Wv^T]
    const __hip_bfloat16* WoT = WqkvT + 3 * (size_t)D * D;
    const __hip_bfloat16* W1T = WoT + (size_t)D * D;
    const __hip_bfloat16* W2T = W1T + (size_t)D * DFF;
    gemm_bt<true, false, false, true><<<dim3(3 * D / 128, M / 128), blk, 0, stream>>>(
        xb, WqkvT, bqkv + (size_t)l * 3 * D, qkvb, M, 3 * D, D);
    attn_kernel<<<dim3(512), blk, 0, stream>>>(qkvb, ob, M);
    // O-proj: split-K x2; bf16 partials p0 (=qkvb, dead) + p1 (=yf); LN1 sums (+bias bo)
    gemm_sk<true><<<dim3(D / 128, M / 128, 2), blk, 0, stream>>>(
        ob, WoT, p0, p1, M, D, D);
    residual_ln<<<dim3(M), blk, 0, stream>>>(
        xf, p0, p1, bo + (size_t)l * D,
        g1 + (size_t)l * D, be1 + (size_t)l * D, xf, xb);
    gemm_bt<true, true, false, false><<<dim3(DFF / 128, M / 128), blk, 0, stream>>>(
        xb, W1T, b1 + (size_t)l * DFF, hb, M, DFF, D);
    // FFN2: split-K x2; bf16 partials; LN2 sums (+bias b2)
    gemm_sk<false><<<dim3(D / 128, M / 128, 2), blk, 0, stream>>>(
        hb, W2T, p0, p1, M, D, DFF);
    residual_ln<<<dim3(M), blk, 0, stream>>>(
        xf, p0, p1, b2 + (size_t)l * D,
        g2 + (size_t)l * D, be2 + (size_t)l * D, xf, xb);
  }

  hipMemcpyAsync(d_out, xf, (size_t)M * D * sizeof(float), hipMemcpyDeviceToDevice, stream);
}

// Round 20
// 1602.222 us; speedup vs baseline: 2.0435x; 1.0418x over previous
//
#include <hip/hip_runtime.h>
#include <hip/hip_bf16.h>

#define DEV __device__ __forceinline__

typedef __attribute__((ext_vector_type(8))) __bf16 bf16x8;
typedef __attribute__((ext_vector_type(4))) float f32x4;
typedef __attribute__((ext_vector_type(4))) short short4v;

DEV void gload_lds16(const void* g, void* l) {
  __builtin_amdgcn_global_load_lds((const __attribute__((address_space(1))) void*)g,
                                   (__attribute__((address_space(3))) void*)l, 16, 0, 0);
}

DEV short f2bf_s(float f) {
  __hip_bfloat16 h = __float2bfloat16(f);
  return __builtin_bit_cast(short, h);
}

DEV float bf2f(short s) {
  unsigned int u = ((unsigned int)(unsigned short)s) << 16;
  return __builtin_bit_cast(float, u);
}

// ---------------- weight prep: fp32 [L][K][N] -> bf16 [L][N][K] (optionally scaled) ------
__global__ __launch_bounds__(256)
void transpose_to_bf16(const float* __restrict__ src, __hip_bfloat16* __restrict__ dst,
                       int K, int N, size_t srcLayerStride, size_t dstLayerStride,
                       float scale) {
  __shared__ float t[32][33];
  const int n0 = blockIdx.x * 32, k0 = blockIdx.y * 32;
  const float* s = src + (size_t)blockIdx.z * srcLayerStride;
  __hip_bfloat16* d = dst + (size_t)blockIdx.z * dstLayerStride;
  const int tx = threadIdx.x & 31, ty = threadIdx.x >> 5;  // 32 x 8
#pragma unroll
  for (int j = 0; j < 4; ++j)
    t[ty + j * 8][tx] = s[(size_t)(k0 + ty + j * 8) * N + n0 + tx];
  __syncthreads();
#pragma unroll
  for (int j = 0; j < 4; ++j)
    d[(size_t)(n0 + ty + j * 8) * K + k0 + tx] = __float2bfloat16(t[tx][ty + j * 8] * scale);
}

// ---------------- pack QKV biases: [L][3072] = [bq*s | bk | bv] ----------------
__global__ __launch_bounds__(256)
void pack_qkv_bias(const float* __restrict__ bq, const float* __restrict__ bk,
                   const float* __restrict__ bv, float* __restrict__ out, float qs) {
  int idx = blockIdx.x * 256 + threadIdx.x;  // L*3072 total
  int l = idx / 3072, j = idx % 3072;
  float v;
  if (j < 1024) v = bq[l * 1024 + j] * qs;
  else if (j < 2048) v = bk[l * 1024 + j - 1024];
  else v = bv[l * 1024 + j - 2048];
  out[idx] = v;
}

// ---------------- x init: bf16 shadow only (residual carried in bf16) ----------------
__global__ __launch_bounds__(256)
void init_x(const float* __restrict__ xin, __hip_bfloat16* __restrict__ xb, int n4) {
  int i = blockIdx.x * 256 + threadIdx.x;
  if (i < n4) {
    float4 v = ((const float4*)xin)[i];
    __hip_bfloat16* o = xb + (size_t)i * 4;
    o[0] = __float2bfloat16(v.x); o[1] = __float2bfloat16(v.y);
    o[2] = __float2bfloat16(v.z); o[3] = __float2bfloat16(v.w);
  }
}

// ---------------- GEMM (single-buffer, m97 structure): multi-block/CU grids ----------------
// AHM: A physically head-major [K/64][M][64]
// CHM: C physically head-major. For the QKV GEMM (CHM=true):
//   cols <  2048 (Q,K thirds): [col/64][M][64]   (row-major per head)
//   cols >= 2048 (V third):    [col/64][64][M]   (COLUMN-major per head) — attn then
//   stages V with dense b128 loads (transpose done for free in this epilogue).
template <bool OUT_BF16, bool RELU, bool AHM, bool CHM>
__global__ __launch_bounds__(256, 2)
void gemm_bt(const __hip_bfloat16* __restrict__ A, const __hip_bfloat16* __restrict__ Bt,
             const float* __restrict__ bias, void* __restrict__ Cout,
             int M, int N, int K) {
  __shared__ __align__(16) short lA[128 * 64];
  __shared__ __align__(16) short lB[128 * 64];
  const int tid = threadIdx.x;
  const int lane = tid & 63, w = tid >> 6;
  const int m0 = blockIdx.y * 128, n0 = blockIdx.x * 128;
  const int wr = w >> 1, wc = w & 1;
  const int lr = lane & 15, lg = lane >> 4;
  const int srow = lane >> 3, scol = (lane & 7) * 8;
  f32x4 acc[4][4] = {};
  const short* Asrc = (const short*)A;
  const short* Bsrc = (const short*)Bt;
  for (int k0 = 0; k0 < K; k0 += 64) {
#pragma unroll
    for (int i = 0; i < 4; ++i) {
      int s = w * 4 + i;
      const short* ap;
      if (AHM)
        ap = Asrc + ((size_t)(k0 >> 6) * M + (m0 + s * 8 + srow)) * 64 + scol;
      else
        ap = Asrc + (size_t)(m0 + s * 8 + srow) * K + k0 + scol;
      gload_lds16(ap, lA + s * 512);
    }
#pragma unroll
    for (int i = 0; i < 4; ++i) {
      int s = w * 4 + i;
      gload_lds16(Bsrc + (size_t)(n0 + s * 8 + srow) * K + k0 + scol, lB + s * 512);
    }
    __syncthreads();
#pragma unroll
    for (int kk = 0; kk < 2; ++kk) {
      const int lk = kk * 32 + lg * 8;
      bf16x8 af[4], bfr[4];
#pragma unroll
      for (int mr = 0; mr < 4; ++mr)
        af[mr] = *(const bf16x8*)&lA[(wr * 64 + mr * 16 + lr) * 64 + lk];
#pragma unroll
      for (int nc = 0; nc < 4; ++nc)
        bfr[nc] = *(const bf16x8*)&lB[(wc * 64 + nc * 16 + lr) * 64 + lk];
#pragma unroll
      for (int mr = 0; mr < 4; ++mr)
#pragma unroll
        for (int nc = 0; nc < 4; ++nc)
          acc[mr][nc] = __builtin_amdgcn_mfma_f32_16x16x32_bf16(af[mr], bfr[nc], acc[mr][nc], 0, 0, 0);
    }
    __syncthreads();
  }
  if (CHM && n0 >= 2048) {
    // V third: column-major per head. 4 consecutive rows pack into one 8B store.
#pragma unroll
    for (int mr = 0; mr < 4; ++mr)
#pragma unroll
      for (int nc = 0; nc < 4; ++nc) {
        const int col = n0 + wc * 64 + nc * 16 + lr;
        const float bv = bias[col];
        const int row0 = m0 + wr * 64 + mr * 16 + lg * 4;
        short4v pack;
#pragma unroll
        for (int r = 0; r < 4; ++r) pack[r] = f2bf_s(acc[mr][nc][r] + bv);
        *(short4v*)((short*)Cout + ((size_t)(col >> 6) * 64 + (col & 63)) * M + row0) = pack;
      }
    return;
  }
#pragma unroll
  for (int mr = 0; mr < 4; ++mr)
#pragma unroll
    for (int nc = 0; nc < 4; ++nc) {
      const int col = n0 + wc * 64 + nc * 16 + lr;
      const float bv = bias[col];
#pragma unroll
      for (int r = 0; r < 4; ++r) {
        const int row = m0 + wr * 64 + mr * 16 + lg * 4 + r;
        float vv = acc[mr][nc][r] + bv;
        if (RELU) vv = fmaxf(vv, 0.f);
        size_t cidx;
        if (CHM) cidx = ((size_t)(col >> 6) * M + row) * 64 + (col & 63);
        else cidx = (size_t)row * N + col;
        if (OUT_BF16)
          ((__hip_bfloat16*)Cout)[cidx] = __float2bfloat16(vv);
        else
          ((float*)Cout)[cidx] = vv;
      }
    }
}

// ---------------- split-K GEMM (2-phase dbuf, z = K-half; no bias) ----------------
// For N=1024 GEMMs (O-proj AHM=true, FFN2 AHM=false). 512 blocks = 2/CU.
// bf16 partials to TWO DISJOINT dead buffers C0/C1 (r14 lesson: never alias A).
template <bool AHM>
__global__ __launch_bounds__(256, 2)
void gemm_sk(const __hip_bfloat16* __restrict__ A, const __hip_bfloat16* __restrict__ Bt,
             __hip_bfloat16* __restrict__ C0, __hip_bfloat16* __restrict__ C1,
             int M, int N, int K) {
  __shared__ __align__(16) short lA[2][128 * 64];
  __shared__ __align__(16) short lB[2][128 * 64];
  const int tid = threadIdx.x;
  const int lane = tid & 63, w = tid >> 6;
  const int m0 = blockIdx.y * 128, n0 = blockIdx.x * 128;
  const int z = blockIdx.z;
  const int Ksub = K >> 1, kbase = z * Ksub;
  const int wr = w >> 1, wc = w & 1;
  const int lr = lane & 15, lg = lane >> 4;
  const int srow = lane >> 3, scol = (lane & 7) * 8;
  f32x4 acc[4][4] = {};
  const short* Asrc = (const short*)A;
  const short* Bsrc = (const short*)Bt;
  const int KT = Ksub >> 6;

  auto stage = [&](int buf, int t) {
    const int kc = kbase + t * 64;
#pragma unroll
    for (int i = 0; i < 4; ++i) {
      int s = w * 4 + i;
      const short* ap;
      if (AHM)
        ap = Asrc + ((size_t)(kc >> 6) * M + (m0 + s * 8 + srow)) * 64 + scol;
      else
        ap = Asrc + (size_t)(m0 + s * 8 + srow) * K + kc + scol;
      gload_lds16(ap, &lA[buf][s * 512]);
      gload_lds16(Bsrc + (size_t)(n0 + s * 8 + srow) * K + kc + scol, &lB[buf][s * 512]);
    }
  };

  stage(0, 0);
  __syncthreads();

  int cur = 0;
  for (int t = 0; t < KT; ++t) {
    if (t + 1 < KT) stage(cur ^ 1, t + 1);
    const short* cA = lA[cur];
    const short* cB = lB[cur];
#pragma unroll
    for (int kk = 0; kk < 2; ++kk) {
      const int lk = kk * 32 + lg * 8;
      bf16x8 af[4], bfr[4];
#pragma unroll
      for (int mr = 0; mr < 4; ++mr)
        af[mr] = *(const bf16x8*)&cA[(wr * 64 + mr * 16 + lr) * 64 + lk];
#pragma unroll
      for (int nc = 0; nc < 4; ++nc)
        bfr[nc] = *(const bf16x8*)&cB[(wc * 64 + nc * 16 + lr) * 64 + lk];
      __builtin_amdgcn_s_setprio(1);
#pragma unroll
      for (int mr = 0; mr < 4; ++mr)
#pragma unroll
        for (int nc = 0; nc < 4; ++nc)
          acc[mr][nc] = __builtin_amdgcn_mfma_f32_16x16x32_bf16(af[mr], bfr[nc], acc[mr][nc], 0, 0, 0);
      __builtin_amdgcn_s_setprio(0);
    }
    __syncthreads();
    cur ^= 1;
  }

  __hip_bfloat16* Cz = z ? C1 : C0;
#pragma unroll
  for (int mr = 0; mr < 4; ++mr)
#pragma unroll
    for (int nc = 0; nc < 4; ++nc) {
      const int col = n0 + wc * 64 + nc * 16 + lr;
#pragma unroll
      for (int r = 0; r < 4; ++r) {
        const int row = m0 + wr * 64 + mr * 16 + lg * 4 + r;
        Cz[(size_t)row * N + col] = __float2bfloat16(acc[mr][nc][r]);
      }
    }
}

// ---------------- flash attention: Q,K head-major [.][M][64]; V COLUMN-major [.][64][M] ---
// EXACT round-16 version (measured 87us): 4-wave blocks, b128 K+V staging, lP [128][64]
// wave-private, two-half exp||PV interleave, XCD head-pinning.
// Loads issue-and-consume (DO NOT prefetch — r5/r9 13x overfetch).
__global__ __launch_bounds__(256, 2)
void attn_kernel(const __hip_bfloat16* __restrict__ qkv_hm, __hip_bfloat16* __restrict__ o_hm,
                 int Mtot) {
  const int S = 2048;
  __shared__ __align__(16) short lK[128 * 64];    // [key][64],  swz chunk ^ (key&7)
  __shared__ __align__(16) short lVt[64 * 128];   // [d][128],   swz chunk ^ (d&15)
  __shared__ __align__(16) short lP[128 * 64];    // [qr][64],   swz chunk ^ (qr&7); wave-private rows
  const int tid = threadIdx.x, lane = tid & 63, w = tid >> 6;
  const int bid = blockIdx.x;
  const int xcd = bid & 7, u = bid >> 3;
  const int gh = (u >> 4) * 8 + xcd;   // 0..31 = (b,h)
  const int qt = u & 15;
  const int b = gh >> 4, h = gh & 15;
  const int lr = lane & 15, lg = lane >> 4;

  const short* qp = (const short*)qkv_hm + (size_t)h * Mtot * 64;
  const short* kp = (const short*)qkv_hm + (size_t)(16 + h) * Mtot * 64;
  const short* vp = (const short*)qkv_hm + (size_t)(32 + h) * Mtot * 64;  // [64][M]

  const size_t qrow0 = (size_t)b * S + (size_t)qt * 128 + w * 32;
  bf16x8 qf[2][2];
#pragma unroll
  for (int mr = 0; mr < 2; ++mr)
#pragma unroll
    for (int kk = 0; kk < 2; ++kk)
      qf[mr][kk] = *(const bf16x8*)(qp + (qrow0 + mr * 16 + lr) * 64 + kk * 32 + lg * 8);

  f32x4 oacc[2][4] = {};
  float mrun[2][4], lrun[2][4];
#pragma unroll
  for (int mr = 0; mr < 2; ++mr)
#pragma unroll
    for (int r = 0; r < 4; ++r) { mrun[mr][r] = -1e30f; lrun[mr][r] = 0.f; }

  for (int kt = 0; kt < S / 128; ++kt) {
    const size_t krow0 = (size_t)b * S + (size_t)kt * 128;
    // ---- global loads (issue-and-consume: self-synchronizing; DO NOT prefetch) ----
    bf16x8 kreg[4], vreg[4];
#pragma unroll
    for (int i = 0; i < 4; ++i) {
      int slot = tid + 256 * i;  // 1024 16B-chunks: 128 keys x 8
      kreg[i] = *(const bf16x8*)(kp + krow0 * 64 + slot * 8);
    }
#pragma unroll
    for (int i = 0; i < 4; ++i) {
      int slot = tid + 256 * i;  // 1024 16B-chunks: 64 d-rows x 16
      int d = slot >> 4, ck = slot & 15;
      vreg[i] = *(const bf16x8*)(vp + (size_t)d * Mtot + krow0 + ck * 8);
    }
    // ---- LDS writes (both b128, swizzled) ----
#pragma unroll
    for (int i = 0; i < 4; ++i) {
      int slot = tid + 256 * i;
      int r = slot >> 3, c = slot & 7;
      *(bf16x8*)&lK[r * 64 + ((c ^ (r & 7)) << 3)] = kreg[i];
    }
#pragma unroll
    for (int i = 0; i < 4; ++i) {
      int slot = tid + 256 * i;
      int d = slot >> 4, ck = slot & 15;
      *(bf16x8*)&lVt[d * 128 + ((ck ^ (d & 15)) << 3)] = vreg[i];
    }
    __syncthreads();

    // ---- QK^T (1/sqrt(dk) pre-folded into Wq/bq) ----
    f32x4 sf[2][8] = {};
    __builtin_amdgcn_s_setprio(1);
#pragma unroll
    for (int kk = 0; kk < 2; ++kk) {
      bf16x8 bfr[8];
#pragma unroll
      for (int nb = 0; nb < 8; ++nb)
        bfr[nb] = *(const bf16x8*)&lK[(nb * 16 + lr) * 64 + (((kk * 4 + lg) ^ (lr & 7)) << 3)];
#pragma unroll
      for (int mr = 0; mr < 2; ++mr)
#pragma unroll
        for (int nb = 0; nb < 8; ++nb)
          sf[mr][nb] = __builtin_amdgcn_mfma_f32_16x16x32_bf16(qf[mr][kk], bfr[nb], sf[mr][nb], 0, 0, 0);
    }
    __builtin_amdgcn_s_setprio(0);

    // ---- row max over ALL keys; rescale oacc ----
    float ls[2][4];
#pragma unroll
    for (int mr = 0; mr < 2; ++mr) {
      float pm[4] = {-1e30f, -1e30f, -1e30f, -1e30f};
#pragma unroll
      for (int nb = 0; nb < 8; ++nb)
#pragma unroll
        for (int r = 0; r < 4; ++r) pm[r] = fmaxf(pm[r], sf[mr][nb][r]);
#pragma unroll
      for (int off = 1; off < 16; off <<= 1)
#pragma unroll
        for (int r = 0; r < 4; ++r) pm[r] = fmaxf(pm[r], __shfl_xor(pm[r], off));
#pragma unroll
      for (int r = 0; r < 4; ++r) {
        float nm = fmaxf(mrun[mr][r], pm[r]);
        float fac = __expf(mrun[mr][r] - nm);
        mrun[mr][r] = nm;
        lrun[mr][r] *= fac;
        ls[mr][r] = 0.f;
#pragma unroll
        for (int nd = 0; nd < 4; ++nd) oacc[mr][nd][r] *= fac;
      }
    }

    // ---- two key-halves: {exp + lP write} then {PV 2 kk}; PV MFMAs overlap next exps ----
#pragma unroll
    for (int half = 0; half < 2; ++half) {
#pragma unroll
      for (int mr = 0; mr < 2; ++mr)
#pragma unroll
        for (int nb = half * 4; nb < half * 4 + 4; ++nb)
#pragma unroll
          for (int r = 0; r < 4; ++r) {
            float p = __expf(sf[mr][nb][r] - mrun[mr][r]);
            ls[mr][r] += p;
            const int rr = w * 32 + mr * 16 + lg * 4 + r;
            const int c = (nb - half * 4) * 16 + lr;  // half-local column 0..63
            lP[rr * 64 + (((c >> 3) ^ (rr & 7)) << 3) + (c & 7)] = f2bf_s(p);
          }
      __builtin_amdgcn_s_setprio(1);
#pragma unroll
      for (int kkh = 0; kkh < 2; ++kkh) {
        const int kkg = half * 2 + kkh;
        bf16x8 pa[2], bv[4];
#pragma unroll
        for (int mr = 0; mr < 2; ++mr) {
          const int rr = w * 32 + mr * 16 + lr;
          pa[mr] = *(const bf16x8*)&lP[rr * 64 + (((kkh * 4 + lg) ^ (rr & 7)) << 3)];
        }
#pragma unroll
        for (int nd = 0; nd < 4; ++nd) {
          const int rd = nd * 16 + lr;
          bv[nd] = *(const bf16x8*)&lVt[rd * 128 + (((kkg * 4 + lg) ^ lr) << 3)];
        }
#pragma unroll
        for (int mr = 0; mr < 2; ++mr)
#pragma unroll
          for (int nd = 0; nd < 4; ++nd)
            oacc[mr][nd] = __builtin_amdgcn_mfma_f32_16x16x32_bf16(pa[mr], bv[nd], oacc[mr][nd], 0, 0, 0);
      }
      __builtin_amdgcn_s_setprio(0);
    }

    // ---- deferred sum reduce ----
#pragma unroll
    for (int mr = 0; mr < 2; ++mr) {
#pragma unroll
      for (int off = 1; off < 16; off <<= 1)
#pragma unroll
        for (int r = 0; r < 4; ++r) ls[mr][r] += __shfl_xor(ls[mr][r], off);
#pragma unroll
      for (int r = 0; r < 4; ++r) lrun[mr][r] += ls[mr][r];
    }
    __syncthreads();  // protect lK/lVt/lP overwrite next iteration
  }

  __hip_bfloat16* op = o_hm + (size_t)h * Mtot * 64;
#pragma unroll
  for (int mr = 0; mr < 2; ++mr) {
    float inv[4];
#pragma unroll
    for (int r = 0; r < 4; ++r) inv[r] = 1.0f / lrun[mr][r];
#pragma unroll
    for (int nd = 0; nd < 4; ++nd)
#pragma unroll
      for (int r = 0; r < 4; ++r) {
        size_t row = qrow0 + mr * 16 + lg * 4 + r;
        int col = nd * 16 + lr;
        op[row * 64 + col] = __float2bfloat16(oacc[mr][nd][r] * inv[r]);
      }
  }
}

// ---------------- fused residual + layernorm ----------------
// x residual carried in bf16 (XF32=true only for layer 0's pristine fp32 input).
// y = y0 + y1 + bias (bf16 split-K partials). Writes bf16 x always; fp32 to
// xout_f only when FINAL (last LN writes d_out directly — no end memcpy).
template <bool XF32, bool FINAL>
__global__ __launch_bounds__(256)
void residual_ln(const float* __restrict__ xin_f, const __hip_bfloat16* __restrict__ xin_b,
                 const __hip_bfloat16* __restrict__ y0, const __hip_bfloat16* __restrict__ y1,
                 const float* __restrict__ bias,
                 const float* __restrict__ g, const float* __restrict__ beta,
                 float* __restrict__ xout_f, __hip_bfloat16* __restrict__ xb) {
  const int D = 1024;
  const int row = blockIdx.x, t = threadIdx.x;
  float x0, x1, x2, x3;
  if (XF32) {
    const float4 xv = ((const float4*)(xin_f + (size_t)row * D))[t];
    x0 = xv.x; x1 = xv.y; x2 = xv.z; x3 = xv.w;
  } else {
    const short4v xv = ((const short4v*)((const short*)xin_b + (size_t)row * D))[t];
    x0 = bf2f(xv[0]); x1 = bf2f(xv[1]); x2 = bf2f(xv[2]); x3 = bf2f(xv[3]);
  }
  const short4v y0v = ((const short4v*)((const short*)y0 + (size_t)row * D))[t];
  const short4v y1v = ((const short4v*)((const short*)y1 + (size_t)row * D))[t];
  const float4 bv2 = ((const float4*)bias)[t];
  float va0 = x0 + bf2f(y0v[0]) + bf2f(y1v[0]) + bv2.x;
  float va1 = x1 + bf2f(y0v[1]) + bf2f(y1v[1]) + bv2.y;
  float va2 = x2 + bf2f(y0v[2]) + bf2f(y1v[2]) + bv2.z;
  float va3 = x3 + bf2f(y0v[3]) + bf2f(y1v[3]) + bv2.w;
  __shared__ float red[4];
  float s = va0 + va1 + va2 + va3;
#pragma unroll
  for (int off = 32; off; off >>= 1) s += __shfl_xor(s, off);
  if ((t & 63) == 0) red[t >> 6] = s;
  __syncthreads();
  const float mu = (red[0] + red[1] + red[2] + red[3]) * (1.0f / D);
  __syncthreads();
  float d0 = va0 - mu, d1 = va1 - mu, d2 = va2 - mu, d3 = va3 - mu;
  float ss = d0 * d0 + d1 * d1 + d2 * d2 + d3 * d3;
#pragma unroll
  for (int off = 32; off; off >>= 1) ss += __shfl_xor(ss, off);
  if ((t & 63) == 0) red[t >> 6] = ss;
  __syncthreads();
  const float var = (red[0] + red[1] + red[2] + red[3]) * (1.0f / D);
  const float rstd = rsqrtf(var + 1e-5f);
  const float4 gv = ((const float4*)g)[t];
  const float4 bv = ((const float4*)beta)[t];
  float o0 = d0 * rstd * gv.x + bv.x;
  float o1 = d1 * rstd * gv.y + bv.y;
  float o2 = d2 * rstd * gv.z + bv.z;
  float o3 = d3 * rstd * gv.w + bv.w;
  if (FINAL)
    ((float4*)(xout_f + (size_t)row * D))[t] = make_float4(o0, o1, o2, o3);
  __hip_bfloat16* ob = xb + (size_t)row * D + (size_t)t * 4;
  ob[0] = __float2bfloat16(o0); ob[1] = __float2bfloat16(o1);
  ob[2] = __float2bfloat16(o2); ob[3] = __float2bfloat16(o3);
}

// ---------------- launcher ----------------
extern "C" void kernel_launch(void* const* d_in, const int* in_sizes, int n_in,
                              void* d_out, int out_size, void* d_ws, size_t ws_size,
                              hipStream_t stream) {
  const int L = 6, D = 1024, DFF = 4096, B = 2, S = 2048, M = B * S;
  const float* x_in = (const float*)d_in[0];
  const float* Wq = (const float*)d_in[1];
  const float* bq = (const float*)d_in[2];
  const float* Wk = (const float*)d_in[3];
  const float* bk = (const float*)d_in[4];
  const float* Wv = (const float*)d_in[5];
  const float* bvp = (const float*)d_in[6];
  const float* Wo = (const float*)d_in[7];
  const float* bo = (const float*)d_in[8];
  const float* g1 = (const float*)d_in[9];
  const float* be1 = (const float*)d_in[10];
  const float* W1 = (const float*)d_in[11];
  const float* b1 = (const float*)d_in[12];
  const float* W2 = (const float*)d_in[13];
  const float* b2 = (const float*)d_in[14];
  const float* g2 = (const float*)d_in[15];
  const float* be2 = (const float*)d_in[16];

  char* base = (char*)d_ws;
  size_t off = 0;
  auto carve = [&](size_t bytes) {
    char* p = base + off;
    off += (bytes + 255) & ~(size_t)255;
    return p;
  };
  const size_t LAYER_ELEMS = 4 * (size_t)D * D + 2 * (size_t)D * DFF;  // 12,582,912
  __hip_bfloat16* wT = (__hip_bfloat16*)carve(L * LAYER_ELEMS * 2);
  float* bqkv = (float*)carve((size_t)L * 3 * D * 4);
  __hip_bfloat16* xb = (__hip_bfloat16*)carve((size_t)M * D * 2);
  __hip_bfloat16* qkvb = (__hip_bfloat16*)carve((size_t)M * 3 * D * 2);  // q,k: [h][M][64]; v: [h][64][M]; 24MB
  __hip_bfloat16* ob = (__hip_bfloat16*)carve((size_t)M * D * 2);        // head-major [16][M][64], 8MB
  __hip_bfloat16* hb = (__hip_bfloat16*)carve((size_t)M * DFF * 2);      // 32MB
  __hip_bfloat16* p1buf = (__hip_bfloat16*)carve((size_t)M * D * 2);     // 8MB, partial only
  if (off > ws_size) return;
  // split-K partials (bf16, 8MB each): TWO DISJOINT dead regions, never aliasing
  // the GEMM's A input (r14 lesson). p0 = qkvb (24MB, dead after attn), p1 = p1buf.
  __hip_bfloat16* p0 = qkvb;
  __hip_bfloat16* p1 = p1buf;
  float* outf = (float*)d_out;

  dim3 blk(256);
  const float qscale = 0.03125f;  // 1/sqrt(1024) = 2^-5, exact in bf16
  transpose_to_bf16<<<dim3(D / 32, D / 32, L), blk, 0, stream>>>(
      Wq, wT + 0 * (size_t)D * D, D, D, (size_t)D * D, LAYER_ELEMS, qscale);
  transpose_to_bf16<<<dim3(D / 32, D / 32, L), blk, 0, stream>>>(
      Wk, wT + 1 * (size_t)D * D, D, D, (size_t)D * D, LAYER_ELEMS, 1.0f);
  transpose_to_bf16<<<dim3(D / 32, D / 32, L), blk, 0, stream>>>(
      Wv, wT + 2 * (size_t)D * D, D, D, (size_t)D * D, LAYER_ELEMS, 1.0f);
  transpose_to_bf16<<<dim3(D / 32, D / 32, L), blk, 0, stream>>>(
      Wo, wT + 3 * (size_t)D * D, D, D, (size_t)D * D, LAYER_ELEMS, 1.0f);
  transpose_to_bf16<<<dim3(DFF / 32, D / 32, L), blk, 0, stream>>>(
      W1, wT + 4 * (size_t)D * D, D, DFF, (size_t)D * DFF, LAYER_ELEMS, 1.0f);
  transpose_to_bf16<<<dim3(D / 32, DFF / 32, L), blk, 0, stream>>>(
      W2, wT + 4 * (size_t)D * D + (size_t)D * DFF, DFF, D, (size_t)D * DFF, LAYER_ELEMS, 1.0f);
  pack_qkv_bias<<<dim3(L * 3 * D / 256), blk, 0, stream>>>(bq, bk, bvp, bqkv, qscale);
  init_x<<<dim3(M * D / 4 / 256), blk, 0, stream>>>(x_in, xb, M * D / 4);

  for (int l = 0; l < L; ++l) {
    const __hip_bfloat16* WqkvT = wT + (size_t)l * LAYER_ELEMS;  // rows: [Wq^T|Wk^T|Wv^T]
    const __hip_bfloat16* WoT = WqkvT + 3 * (size_t)D * D;
    const __hip_bfloat16* W1T = WoT + (size_t)D * D;
    const __hip_bfloat16* W2T = W1T + (size_t)D * DFF;
    gemm_bt<true, false, false, true><<<dim3(3 * D / 128, M / 128), blk, 0, stream>>>(
        xb, WqkvT, bqkv + (size_t)l * 3 * D, qkvb, M, 3 * D, D);
    attn_kernel<<<dim3(512), blk, 0, stream>>>(qkvb, ob, M);
    // O-proj: split-K x2; bf16 partials p0 (=qkvb, dead) + p1; LN1 sums (+bias bo)
    gemm_sk<true><<<dim3(D / 128, M / 128, 2), blk, 0, stream>>>(
        ob, WoT, p0, p1, M, D, D);
    if (l == 0)
      residual_ln<true, false><<<dim3(M), blk, 0, stream>>>(
          x_in, nullptr, p0, p1, bo + (size_t)l * D,
          g1 + (size_t)l * D, be1 + (size_t)l * D, nullptr, xb);
    else
      residual_ln<false, false><<<dim3(M), blk, 0, stream>>>(
          nullptr, xb, p0, p1, bo + (size_t)l * D,
          g1 + (size_t)l * D, be1 + (size_t)l * D, nullptr, xb);
    gemm_bt<true, true, false, false><<<dim3(DFF / 128, M / 128), blk, 0, stream>>>(
        xb, W1T, b1 + (size_t)l * DFF, hb, M, DFF, D);
    // FFN2: split-K x2; bf16 partials; LN2 sums (+bias b2); final LN writes d_out
    gemm_sk<false><<<dim3(D / 128, M / 128, 2), blk, 0, stream>>>(
        hb, W2T, p0, p1, M, D, DFF);
    if (l == L - 1)
      residual_ln<false, true><<<dim3(M), blk, 0, stream>>>(
          nullptr, xb, p0, p1, b2 + (size_t)l * D,
          g2 + (size_t)l * D, be2 + (size_t)l * D, outf, xb);
    else
      residual_ln<false, false><<<dim3(M), blk, 0, stream>>>(
          nullptr, xb, p0, p1, b2 + (size_t)l * D,
          g2 + (size_t)l * D, be2 + (size_t)l * D, nullptr, xb);
  }
}